// Round 11
// baseline (262.743 us; speedup 1.0000x reference)
//
#include <hip/hip_runtime.h>

typedef unsigned int u32;
typedef unsigned short u16;
typedef unsigned long long u64;
typedef __attribute__((ext_vector_type(8))) short bh8;   // 8 bf16 (4 VGPRs) MFMA frag
typedef __attribute__((ext_vector_type(4))) float f4;    // 4 fp32 acc

#define HMAX 1024    // max heavy (deg>S) nodes tracked; expected ~65
#define MAXD 128     // max out-degree bucketed; expected max ~58
#define SB_CAP 24576 // src-bin capacity: mean 16384, sigma ~127 -> +64 sigma
#define DB_CAP 6144  // dst-bin capacity: mean 4092, sigma ~64 -> +32 sigma
#define SBCHUNK 8192 // edges per bin block; R8 proved 4096 doubles scatter transactions
#define SPLIT 8      // blocks per src bucket in shist/hfill
#define G1S 72       // gemm1 LDS row stride (64 + 8 pad) -> 18.4KB block
#define DROP_CAP 32768
#define CPAD 16      // pad contended global counters to one per 64B line

__device__ inline f4 mfma16(bh8 a, bh8 b, f4 c) {
  return __builtin_amdgcn_mfma_f32_16x16x32_bf16(a, b, c, 0, 0, 0);
}

// ---------------- threefry2x32 (exact JAX cipher) ----------------
__host__ __device__ inline void tf2x32(u32 k0, u32 k1, u32 x0, u32 x1, u32& o0, u32& o1) {
  u32 ks2 = k0 ^ k1 ^ 0x1BD11BDAu;
#define ROTL32(x,d) (((x)<<(d))|((x)>>(32-(d))))
#define TFR(r) { x0 += x1; x1 = ROTL32(x1,(r)); x1 ^= x0; }
  x0 += k0; x1 += k1;
  TFR(13) TFR(15) TFR(26) TFR(6)
  x0 += k1; x1 += ks2 + 1u;
  TFR(17) TFR(29) TFR(16) TFR(24)
  x0 += ks2; x1 += k0 + 2u;
  TFR(13) TFR(15) TFR(26) TFR(6)
  x0 += k0; x1 += k1 + 3u;
  TFR(17) TFR(29) TFR(16) TFR(24)
  x0 += k1; x1 += ks2 + 4u;
  TFR(13) TFR(15) TFR(26) TFR(6)
  x0 += ks2; x1 += k0 + 5u;
  o0 = x0; o1 = x1;
#undef TFR
#undef ROTL32
}

__device__ inline u16 f2bf(float f) {      // round-to-nearest-even (finite inputs)
  u32 u = __float_as_uint(f);
  return (u16)((u + 0x7FFFu + ((u >> 16) & 1u)) >> 16);
}
__device__ inline float bflo(u32 u) { return __uint_as_float(u << 16); }
__device__ inline float bfhi(u32 u) { return __uint_as_float(u & 0xFFFF0000u); }

// NOTE: parameter named 'wt' (NOT 'w') so member selectors .x/.y/.z/.w don't get captured
#define ACC8(uv, wt) \
  a0 = fmaf(wt, bflo(uv.x), a0); a1 = fmaf(wt, bfhi(uv.x), a1); \
  a2 = fmaf(wt, bflo(uv.y), a2); a3 = fmaf(wt, bfhi(uv.y), a3); \
  a4 = fmaf(wt, bflo(uv.z), a4); a5 = fmaf(wt, bfhi(uv.z), a5); \
  a6 = fmaf(wt, bflo(uv.w), a6); a7 = fmaf(wt, bfhi(uv.w), a7);

// ---------------- mega1: [bin blocks] || [gemm1 blocks] || [W2 prep block] ----------------
// src bins: 128 x 512 nodes (outdeg machinery); dst bins: up to 512 x 128 nodes (CSR sort)
struct BinS { u32 lsrc[128]; u32 lbase[128]; u32 ldst[512]; u32 dbase[512]; };
struct GemS { u16 xs[64 * G1S]; u16 ws[64 * G1S]; };

__global__ __launch_bounds__(256) void k_mega1(const int* __restrict__ ei, int E,
                                               const float* __restrict__ x, int N,
                                               const float* __restrict__ W1, const float* __restrict__ W2,
                                               int* __restrict__ srcCnt, u32* __restrict__ srcRec,
                                               int* __restrict__ dstCnt, u64* __restrict__ dstRec,
                                               u16* __restrict__ h1b, u16* __restrict__ W2t, int nBin) {
  __shared__ __align__(16) char smem[sizeof(GemS)];
  int t = threadIdx.x;
  int bid = blockIdx.x;
  int nGemm = (N + 63) >> 6;

  if (bid < nBin) {
    // ---- bin path: src-bin (u32) + dst-bin (u64); two passes over an 8K-edge chunk ----
    BinS& S = *(BinS*)smem;
    if (t < 128) S.lsrc[t] = 0;
    for (int v = t; v < 512; v += 256) S.ldst[v] = 0;
    __syncthreads();
    int lo = bid * SBCHUNK;
    int hi = min(lo + SBCHUNK, E);
    bool fast = ((E & 3) == 0);

    auto loadE = [&](int e0, int nv, int* sv, int* dv) {
      if (nv == 8 && fast) {
        int4 a0 = *((const int4*)(ei + e0));
        int4 a1 = *((const int4*)(ei + e0 + 4));
        int4 b0 = *((const int4*)(ei + E + e0));
        int4 b1 = *((const int4*)(ei + E + e0 + 4));
        sv[0]=a0.x; sv[1]=a0.y; sv[2]=a0.z; sv[3]=a0.w; sv[4]=a1.x; sv[5]=a1.y; sv[6]=a1.z; sv[7]=a1.w;
        dv[0]=b0.x; dv[1]=b0.y; dv[2]=b0.z; dv[3]=b0.w; dv[4]=b1.x; dv[5]=b1.y; dv[6]=b1.z; dv[7]=b1.w;
      } else {
        for (int j = 0; j < nv; ++j) { sv[j] = ei[e0 + j]; dv[j] = ei[E + e0 + j]; }
      }
    };

    // pass 1: LDS histograms (fire-and-forget atomics)
    for (int sub = 0; sub < SBCHUNK; sub += 2048) {
      int e0 = lo + sub + 8 * t;
      int nv = min(8, hi - e0); if (nv < 0) nv = 0;
      int sv[8], dv[8];
      loadE(e0, nv, sv, dv);
      for (int j = 0; j < nv; ++j) {
        atomicAdd(&S.lsrc[sv[j] >> 9], 1u);
        atomicAdd(&S.ldst[dv[j] >> 7], 1u);
      }
    }
    __syncthreads();
    // pass 2: reserve global bases (padded counters: 1 per 64B line)
    if (t < 128) {
      u32 c = S.lsrc[t];
      if (c) S.lbase[t] = (u32)atomicAdd(&srcCnt[t * CPAD], (int)c);
      S.lsrc[t] = 0;
    }
    for (int v = t; v < 512; v += 256) {
      u32 cd = S.ldst[v];
      if (cd) S.dbase[v] = (u32)atomicAdd(&dstCnt[v * CPAD], (int)cd);
      S.ldst[v] = 0;
    }
    __syncthreads();
    // pass 3: re-read edges (L2/L3-hot), scatter to per-bucket records
    for (int sub = 0; sub < SBCHUNK; sub += 2048) {
      int e0 = lo + sub + 8 * t;
      int nv = min(8, hi - e0); if (nv < 0) nv = 0;
      int sv[8], dv[8];
      loadE(e0, nv, sv, dv);
      for (int j = 0; j < nv; ++j) {
        int s = sv[j], d = dv[j];
        u32 i = (u32)(e0 + j);
        int bs = s >> 9;
        u32 slot = S.lbase[bs] + atomicAdd(&S.lsrc[bs], 1u);
        if (slot < SB_CAP) srcRec[(size_t)bs * SB_CAP + slot] = ((u32)(s & 511) << 21) | i;
        int bd = d >> 7;
        u32 slot2 = S.dbase[bd] + atomicAdd(&S.ldst[bd], 1u);
        if (slot2 < DB_CAP)
          dstRec[(size_t)bd * DB_CAP + slot2] = ((u64)(d & 127) << 37) | ((u64)(u32)s << 21) | i;
      }
    }
  } else if (bid < nBin + nGemm) {
    // ---- gemm1 path: h1 = bf16(x) @ bf16(W1), K-tile 64 (18.4KB LDS) ----
    GemS& G = *(GemS*)smem;
    int wv = t >> 6, lane = t & 63;
    int qd = lane >> 4, md = lane & 15;
    int m0 = (bid - nBin) * 64;
    if (m0 >= N) return;
    f4 acc[4] = {};
    for (int ks = 0; ks < 256; ks += 64) {
      __syncthreads();
#pragma unroll
      for (int i = 0; i < 4; ++i) {             // stage x[m0..+63][ks..+63] -> bf16 LDS (1024 float4)
        int f = t + 256 * i;
        int r = f >> 4, c4 = f & 15;
        int grow = m0 + r; if (grow >= N) grow = N - 1;
        float4 v = ((const float4*)x)[(size_t)grow * 64 + (ks >> 2) + c4];
        u32 p0 = (u32)f2bf(v.x) | ((u32)f2bf(v.y) << 16);
        u32 p1 = (u32)f2bf(v.z) | ((u32)f2bf(v.w) << 16);
        *((uint2*)(G.xs + r * G1S + c4 * 4)) = make_uint2(p0, p1);
      }
#pragma unroll
      for (int i = 0; i < 4; ++i) {             // stage W1[ks..+63][0..63] fp32 -> bf16 n-major
        int f = t + 256 * i;
        int k = f >> 4, c4 = f & 15;
        float4 v = ((const float4*)W1)[(ks + k) * 16 + c4];
        int n0 = c4 * 4;
        G.ws[(n0 + 0) * G1S + k] = f2bf(v.x);
        G.ws[(n0 + 1) * G1S + k] = f2bf(v.y);
        G.ws[(n0 + 2) * G1S + k] = f2bf(v.z);
        G.ws[(n0 + 3) * G1S + k] = f2bf(v.w);
      }
      __syncthreads();
#pragma unroll
      for (int kk = 0; kk < 64; kk += 32) {
        bh8 af = *((const bh8*)(G.xs + (16 * wv + md) * G1S + kk + qd * 8));
#pragma unroll
        for (int nt = 0; nt < 4; ++nt) {
          bh8 bf = *((const bh8*)(G.ws + (nt * 16 + md) * G1S + kk + qd * 8));
          acc[nt] = mfma16(af, bf, acc[nt]);
        }
      }
    }
#pragma unroll
    for (int nt = 0; nt < 4; ++nt)
#pragma unroll
      for (int r = 0; r < 4; ++r) {
        int row = m0 + 16 * wv + qd * 4 + r;
        if (row < N) h1b[(size_t)row * 64 + nt * 16 + md] = f2bf(acc[nt][r]);
      }
  } else {
    // ---- W2 prep path: W2t[n][k] = bf16(W2[k][n]) ----
    for (int e = t; e < 64 * 128; e += 256) {
      int n = e & 127, k = e >> 7;
      W2t[n * 64 + k] = f2bf(W2[k * 128 + n]);
    }
  }
}

// ---------------- shist: partial LDS histograms -> global outdegB ----------------
__global__ __launch_bounds__(256) void k_shist(const int* __restrict__ srcCnt, const u32* __restrict__ srcRec,
                                               int* __restrict__ outdegB) {
  int bk = blockIdx.x >> 3;          // / SPLIT
  int part = blockIdx.x & (SPLIT - 1);
  int total = min(srcCnt[bk * CPAD], SB_CAP);
  int lo = total * part / SPLIT;
  int hi = total * (part + 1) / SPLIT;
  __shared__ u32 cnt[512];
  int t = threadIdx.x;
  cnt[t] = 0; cnt[t + 256] = 0;
  __syncthreads();
  const u32* R = srcRec + (size_t)bk * SB_CAP;
  for (int i = lo + t; i < hi; i += 256) atomicAdd(&cnt[R[i] >> 21], 1u);
  __syncthreads();
  int base = bk * 512;
  for (int v = t; v < 512; v += 256) {
    u32 c = cnt[v];
    if (c) atomicAdd(&outdegB[base + v], (int)c);
  }
}

// ---------------- hdetect: heavy-id assignment + dst-bucket scan (parallel) ----------------
__global__ __launch_bounds__(256) void k_hdetect(const int* __restrict__ outdegB, u32* __restrict__ idAB,
                                                 int* __restrict__ hcA, int* __restrict__ hcB,
                                                 const int* __restrict__ dstCnt, int* __restrict__ bucketBase,
                                                 int* __restrict__ dptr, int nbD, int N) {
  int t = threadIdx.x;
  if (blockIdx.x == 0) {
    __shared__ int sc[512], tp[512];
    for (int i = t; i < 512; i += 256) sc[i] = (i < nbD) ? min(dstCnt[i * CPAD], DB_CAP) : 0;
    __syncthreads();
    for (int off = 1; off < 512; off <<= 1) {
      for (int i = t; i < 512; i += 256) tp[i] = sc[i] + ((i >= off) ? sc[i - off] : 0);
      __syncthreads();
      for (int i = t; i < 512; i += 256) sc[i] = tp[i];
      __syncthreads();
    }
    for (int i = t; i < 512; i += 256) {
      if (i < nbD) bucketBase[i] = (i == 0) ? 0 : sc[i - 1];
    }
    if (t == 0) {
      int tot = sc[nbD - 1];
      bucketBase[nbD] = tot;
      dptr[N] = tot;   // == E (absent overflow)
    }
  }
  int v = blockIdx.x * 256 + t;
  if (v >= N) return;
  int dg = outdegB[v];
  u32 pk = 0;
  if (dg > 50) {
    int idb = atomicAdd(hcB, 1);
    if (idb < HMAX) pk = (u32)(idb + 1);
    if (dg > 100) {
      int ida = atomicAdd(hcA, 1);
      if (ida < HMAX) pk |= (u32)(ida + 1) << 16;
    }
  }
  idAB[v] = pk;
}

// ---------------- hfill: PRNG-bucket heavy edges ----------------
__global__ __launch_bounds__(256) void k_hfill(const int* __restrict__ srcCnt, const u32* __restrict__ srcRec,
                                               const u32* __restrict__ idAB,
                                               int* __restrict__ bcA, u64* __restrict__ bukA,
                                               int* __restrict__ bcB, u64* __restrict__ bukB,
                                               u32 kaA, u32 kbA, u32 kaB, u32 kbB) {
  int bk = blockIdx.x >> 3;
  int part = blockIdx.x & (SPLIT - 1);
  int total = min(srcCnt[bk * CPAD], SB_CAP);
  int lo = total * part / SPLIT;
  int hi = total * (part + 1) / SPLIT;
  const u32* R = srcRec + (size_t)bk * SB_CAP;
  int base = bk * 512;
  for (int i = lo + threadIdx.x; i < hi; i += 256) {
    u32 r = R[i];
    u32 pk = idAB[base + (int)(r >> 21)];
    if (pk) {
      u32 e = r & 0x1FFFFFu;
      int idb = (int)(pk & 0xFFFFu) - 1;
      if (idb >= 0) {
        u32 w0, w1; tf2x32(kaB, kbB, 0u, e, w0, w1);
        int slot = atomicAdd(&bcB[idb], 1);
        if (slot < MAXD) bukB[(size_t)idb * MAXD + slot] = ((u64)((w0 ^ w1) >> 9) << 32) | e;
      }
      int ida = (int)(pk >> 16) - 1;
      if (ida >= 0) {
        u32 w0, w1; tf2x32(kaA, kbA, 0u, e, w0, w1);
        int slot = atomicAdd(&bcA[ida], 1);
        if (slot < MAXD) bukA[(size_t)ida * MAXD + slot] = ((u64)((w0 ^ w1) >> 9) << 32) | e;
      }
    }
  }
}

// ---------------- rank2: drop rank >= S -> append (eid | bit<<21) to dropList ----------------
__global__ __launch_bounds__(256) void k_rank2(const int* __restrict__ hcA, const int* __restrict__ bcA,
                                               const u64* __restrict__ bukA,
                                               const int* __restrict__ hcB, const int* __restrict__ bcB,
                                               const u64* __restrict__ bukB,
                                               int* __restrict__ dropCnt, u32* __restrict__ dropList) {
  bool isA = blockIdx.x < (HMAX / 4);
  int bx = isA ? blockIdx.x : blockIdx.x - HMAX / 4;
  const int* hcount = isA ? hcA : hcB;
  const int* bcount = isA ? bcA : bcB;
  const u64* bucket = isA ? bukA : bukB;
  int S = isA ? 100 : 50;
  u32 bit = isA ? 1u : 2u;
  int wid = (bx * 256 + (int)threadIdx.x) >> 6;
  int lane = threadIdx.x & 63;
  int hc = hcount[0]; if (hc > HMAX) hc = HMAX;
  if (wid >= hc) return;
  int d = bcount[wid]; if (d > MAXD) d = MAXD;
  const u64* B = bucket + (size_t)wid * MAXD;
  for (int i = lane; i < d; i += 64) {
    u64 ki = B[i];
    int rank = 0;
    for (int j = 0; j < d; ++j) rank += (B[j] < ki) ? 1 : 0;
    if (rank >= S) {
      int idx = atomicAdd(dropCnt, 1);
      if (idx < DROP_CAP) dropList[idx] = ((u32)ki & 0x1FFFFFu) | (bit << 21);
    }
  }
}

// ---------------- phase2: per-bucket counting sort from dstRec -> entries/dptr/dinv ----------------
// dstRec = dstlow7(37:44) | src(21:36) | eid(0:20); single global pass, pass-2 from LDS cache
__global__ __launch_bounds__(256) void k_phase2(const int* __restrict__ bucketBase,
                                                const int* __restrict__ dstCnt,
                                                const u64* __restrict__ dstRec,
                                                const int* __restrict__ dropCnt,
                                                const u32* __restrict__ dropList,
                                                u32* __restrict__ entries, int* __restrict__ dptr,
                                                float* __restrict__ dinv1, float* __restrict__ dinv2, int N) {
  int b = blockIdx.x;
  int base = bucketBase[b];
  int cnt0 = min(dstCnt[b * CPAD], DB_CAP);
  const u64* R = dstRec + (size_t)b * DB_CAP;
  __shared__ u32 cnt[128];
  __shared__ u32 htab[4096];
  __shared__ u32 ws2[2];
  __shared__ u32 earr[DB_CAP];     // per-edge decode cache: src(0:15)|drop(16:17)|dl(18:24)
  int t = threadIdx.x;
  if (t < 128) cnt[t] = 0;
  for (int i = t; i < 4096; i += 256) htab[i] = 0xFFFFFFFFu;
  __syncthreads();
  int dc = min(dropCnt[0], 3072);
  for (int i = t; i < dc; i += 256) {
    u32 pk = dropList[i];
    u32 key = pk & 0x1FFFFFu;
    u32 h = (key * 2654435761u) >> 20;
    while (true) {
      u32 old = atomicCAS(&htab[h], 0xFFFFFFFFu, pk);
      if (old == 0xFFFFFFFFu) break;
      if ((old & 0x1FFFFFu) == key) { atomicOr(&htab[h], pk & 0x00600000u); break; }
      h = (h + 1) & 4095;
    }
  }
  __syncthreads();
  // pass 1: packed histogram total(0:9) | keep1(10:19) | keep2(20:29); cache decode in LDS
  for (int i = t; i < cnt0; i += 256) {
    u64 r = R[i];
    u32 dl = (u32)(r >> 37) & 127u;
    u32 key = (u32)r & 0x1FFFFFu;
    u32 drop = 0;
    u32 h = (key * 2654435761u) >> 20;
    while (true) {
      u32 v = htab[h];
      if (v == 0xFFFFFFFFu) break;
      if ((v & 0x1FFFFFu) == key) { drop = (v >> 21) & 3u; break; }
      h = (h + 1) & 4095;
    }
    u32 src = (u32)(r >> 21) & 0xFFFFu;
    earr[i] = src | (drop << 16) | (dl << 18);
    u32 add = 1u + ((1u - (drop & 1u)) << 10) + ((1u - ((drop >> 1) & 1u)) << 20);
    atomicAdd(&cnt[dl], add);
  }
  __syncthreads();
  u32 c0 = (t < 128) ? cnt[t] : 0;
  u32 tot = c0 & 1023u;
  int lane = t & 63, w = t >> 6;
  u32 incl = tot;
  for (int off = 1; off < 64; off <<= 1) {
    u32 nbv = (u32)__shfl_up((int)incl, off, 64);
    if (lane >= off) incl += nbv;
  }
  if (lane == 63 && w == 0) ws2[0] = incl;
  __syncthreads();
  u32 excl = incl - tot + ((w == 1) ? ws2[0] : 0u);
  int v0 = b * 128 + t;
  if (t < 128 && v0 < N) {
    dptr[v0] = base + (int)excl;
    dinv1[v0] = 1.0f / sqrtf((float)(((c0 >> 10) & 1023u) + 1u));
    dinv2[v0] = 1.0f / sqrtf((float)(((c0 >> 20) & 1023u) + 1u));
  }
  __syncthreads();
  if (t < 128) cnt[t] = excl;
  __syncthreads();
  // pass 2: scatter from LDS cache (no dstRec re-read, no re-probe)
  for (int i = t; i < cnt0; i += 256) {
    u32 p = earr[i];
    u32 dl = (p >> 18) & 127u;
    u32 drop = (p >> 16) & 3u;
    u32 src = p & 0xFFFFu;
    u32 slot = atomicAdd(&cnt[dl], 1u);
    entries[base + slot] = src | ((drop & 1u) ? 0u : (1u << 30)) | ((drop & 2u) ? 0u : (1u << 31));
  }
}

// ---------------- conv1: aggregate h1 + bias + relu + L2 normalize -> bf16 hnb ----------------
// wave per dst; 8 groups x 8 lanes; R11: group-direct entry/dinv loads (zero in-loop shuffles)
__global__ __launch_bounds__(256) void k_conv1n(const int* __restrict__ ptr, const u32* __restrict__ entries,
                                                const float* __restrict__ dinv1, const uint4* __restrict__ h1q,
                                                const float* __restrict__ b1, uint4* __restrict__ hnbq, int N) {
  int wid = (blockIdx.x * 256 + threadIdx.x) >> 6;
  if (wid >= N) return;
  int lane = threadIdx.x & 63;
  int lo8 = lane & 7, grp = lane >> 3;
  int beg = ptr[wid], end = ptr[wid + 1];
  float a0 = 0.f, a1 = 0.f, a2 = 0.f, a3 = 0.f, a4 = 0.f, a5 = 0.f, a6 = 0.f, a7 = 0.f;
  for (int cb = beg; cb < end; cb += 64) {
    int nq = (min(64, end - cb) + 7) >> 3;
#define GDC(k) \
    float w##k = 0.f; int s##k = 0; uint4 u##k = make_uint4(0u, 0u, 0u, 0u); \
    if (nq > (k)) { \
      int ex = cb + grp + 8 * (k); \
      u32 ev = (ex < end) ? entries[ex] : 0u; \
      s##k = (int)(ev & 0xFFFFu); \
      if (ev & (1u << 30)) w##k = dinv1[s##k]; \
      u##k = h1q[(size_t)s##k * 8 + lo8]; \
    }
    GDC(0) GDC(1) GDC(2) GDC(3) GDC(4) GDC(5) GDC(6) GDC(7)
#undef GDC
    ACC8(u0, w0)
    if (nq > 1) { ACC8(u1, w1) }
    if (nq > 2) { ACC8(u2, w2) }
    if (nq > 3) { ACC8(u3, w3) }
    if (nq > 4) { ACC8(u4, w4) }
    if (nq > 5) { ACC8(u5, w5) }
    if (nq > 6) { ACC8(u6, w6) }
    if (nq > 7) { ACC8(u7, w7) }
  }
#pragma unroll
  for (int off = 8; off < 64; off <<= 1) {
    a0 += __shfl_xor(a0, off, 64); a1 += __shfl_xor(a1, off, 64);
    a2 += __shfl_xor(a2, off, 64); a3 += __shfl_xor(a3, off, 64);
    a4 += __shfl_xor(a4, off, 64); a5 += __shfl_xor(a5, off, 64);
    a6 += __shfl_xor(a6, off, 64); a7 += __shfl_xor(a7, off, 64);
  }
  float dv = dinv1[wid];
  uint4 uo = h1q[(size_t)wid * 8 + lo8];
  a0 = fmaf(dv, bflo(uo.x), a0); a1 = fmaf(dv, bfhi(uo.x), a1);
  a2 = fmaf(dv, bflo(uo.y), a2); a3 = fmaf(dv, bfhi(uo.y), a3);
  a4 = fmaf(dv, bflo(uo.z), a4); a5 = fmaf(dv, bfhi(uo.z), a5);
  a6 = fmaf(dv, bflo(uo.w), a6); a7 = fmaf(dv, bfhi(uo.w), a7);
  float4 bbA = ((const float4*)b1)[lo8 * 2];
  float4 bbB = ((const float4*)b1)[lo8 * 2 + 1];
  float o0 = fmaxf(fmaf(dv, a0, bbA.x), 0.f);
  float o1 = fmaxf(fmaf(dv, a1, bbA.y), 0.f);
  float o2 = fmaxf(fmaf(dv, a2, bbA.z), 0.f);
  float o3 = fmaxf(fmaf(dv, a3, bbA.w), 0.f);
  float o4 = fmaxf(fmaf(dv, a4, bbB.x), 0.f);
  float o5 = fmaxf(fmaf(dv, a5, bbB.y), 0.f);
  float o6 = fmaxf(fmaf(dv, a6, bbB.z), 0.f);
  float o7 = fmaxf(fmaf(dv, a7, bbB.w), 0.f);
  float ss = fmaf(o0, o0, fmaf(o1, o1, fmaf(o2, o2, o3 * o3)))
           + fmaf(o4, o4, fmaf(o5, o5, fmaf(o6, o6, o7 * o7)));
#pragma unroll
  for (int off = 1; off < 8; off <<= 1) ss += __shfl_xor(ss, off, 8);
  float sc = 1.f / fmaxf(sqrtf(ss), 1e-12f);
  if (lane < 8) {
    uint4 pv;
    pv.x = (u32)f2bf(o0 * sc) | ((u32)f2bf(o1 * sc) << 16);
    pv.y = (u32)f2bf(o2 * sc) | ((u32)f2bf(o3 * sc) << 16);
    pv.z = (u32)f2bf(o4 * sc) | ((u32)f2bf(o5 * sc) << 16);
    pv.w = (u32)f2bf(o6 * sc) | ((u32)f2bf(o7 * sc) << 16);
    hnbq[(size_t)wid * 8 + lo8] = pv;
  }
}

// ---------------- agg2: aggregate hnb with dinv2 -> bf16 agg2b (group-direct loads) ----------------
__global__ __launch_bounds__(256) void k_agg2(const int* __restrict__ ptr, const u32* __restrict__ entries,
                                              const float* __restrict__ dinv2, const uint4* __restrict__ hnq,
                                              uint4* __restrict__ agg2q, int N) {
  int wid = (blockIdx.x * 256 + threadIdx.x) >> 6;
  if (wid >= N) return;
  int lane = threadIdx.x & 63;
  int lo8 = lane & 7, grp = lane >> 3;
  int beg = ptr[wid], end = ptr[wid + 1];
  float a0 = 0.f, a1 = 0.f, a2 = 0.f, a3 = 0.f, a4 = 0.f, a5 = 0.f, a6 = 0.f, a7 = 0.f;
  for (int cb = beg; cb < end; cb += 64) {
    int nq = (min(64, end - cb) + 7) >> 3;
#define GDA(k) \
    float w##k = 0.f; int s##k = 0; uint4 u##k = make_uint4(0u, 0u, 0u, 0u); \
    if (nq > (k)) { \
      int ex = cb + grp + 8 * (k); \
      u32 ev = (ex < end) ? entries[ex] : 0u; \
      s##k = (int)(ev & 0xFFFFu); \
      if (ev & (1u << 31)) w##k = dinv2[s##k]; \
      u##k = hnq[(size_t)s##k * 8 + lo8]; \
    }
    GDA(0) GDA(1) GDA(2) GDA(3) GDA(4) GDA(5) GDA(6) GDA(7)
#undef GDA
    ACC8(u0, w0)
    if (nq > 1) { ACC8(u1, w1) }
    if (nq > 2) { ACC8(u2, w2) }
    if (nq > 3) { ACC8(u3, w3) }
    if (nq > 4) { ACC8(u4, w4) }
    if (nq > 5) { ACC8(u5, w5) }
    if (nq > 6) { ACC8(u6, w6) }
    if (nq > 7) { ACC8(u7, w7) }
  }
#pragma unroll
  for (int off = 8; off < 64; off <<= 1) {
    a0 += __shfl_xor(a0, off, 64); a1 += __shfl_xor(a1, off, 64);
    a2 += __shfl_xor(a2, off, 64); a3 += __shfl_xor(a3, off, 64);
    a4 += __shfl_xor(a4, off, 64); a5 += __shfl_xor(a5, off, 64);
    a6 += __shfl_xor(a6, off, 64); a7 += __shfl_xor(a7, off, 64);
  }
  float dv = dinv2[wid];
  uint4 uo = hnq[(size_t)wid * 8 + lo8];
  a0 = fmaf(dv, bflo(uo.x), a0); a1 = fmaf(dv, bfhi(uo.x), a1);
  a2 = fmaf(dv, bflo(uo.y), a2); a3 = fmaf(dv, bfhi(uo.y), a3);
  a4 = fmaf(dv, bflo(uo.z), a4); a5 = fmaf(dv, bfhi(uo.z), a5);
  a6 = fmaf(dv, bflo(uo.w), a6); a7 = fmaf(dv, bfhi(uo.w), a7);
  if (lane < 8) {
    uint4 pv;
    pv.x = (u32)f2bf(dv * a0) | ((u32)f2bf(dv * a1) << 16);
    pv.y = (u32)f2bf(dv * a2) | ((u32)f2bf(dv * a3) << 16);
    pv.z = (u32)f2bf(dv * a4) | ((u32)f2bf(dv * a5) << 16);
    pv.w = (u32)f2bf(dv * a6) | ((u32)f2bf(dv * a7) << 16);
    agg2q[(size_t)wid * 8 + lo8] = pv;
  }
}

// ---------------- gemm2f: out = agg2b @ W2 + b2 (MFMA, fused bias, fp32 out) ----------------
#define G2S 72
__global__ __launch_bounds__(256) void k_gemm2f(const u16* __restrict__ aggb, const u16* __restrict__ W2t,
                                                const float* __restrict__ b2, float* __restrict__ out, int N) {
  __shared__ u16 hs[64 * G2S];
  __shared__ u16 ws[128 * G2S];
  int t = threadIdx.x;
  int wv = t >> 6, lane = t & 63;
  int qd = lane >> 4, md = lane & 15;
  int m0 = blockIdx.x * 64;
#pragma unroll
  for (int i = 0; i < 2; ++i) {                 // stage aggb: 64 rows x 64 u16 = 512 uint4
    int cc = t + 256 * i;
    int r = cc >> 3, kc = (cc & 7) * 8;
    int grow = m0 + r; if (grow >= N) grow = N - 1;
    *((uint4*)(hs + r * G2S + kc)) = *((const uint4*)(aggb + (size_t)grow * 64 + kc));
  }
#pragma unroll
  for (int i = 0; i < 4; ++i) {                 // stage W2t (128x64 u16)
    int cc = t + 256 * i;
    int n = cc >> 3, kc = (cc & 7) * 8;
    *((uint4*)(ws + n * G2S + kc)) = *((const uint4*)(W2t + n * 64 + kc));
  }
  __syncthreads();
  f4 acc[8] = {};
#pragma unroll
  for (int kk = 0; kk < 64; kk += 32) {
    bh8 af = *((const bh8*)(hs + (16 * wv + md) * G2S + kk + qd * 8));
#pragma unroll
    for (int nt = 0; nt < 8; ++nt) {
      bh8 bf = *((const bh8*)(ws + (nt * 16 + md) * G2S + kk + qd * 8));
      acc[nt] = mfma16(af, bf, acc[nt]);
    }
  }
#pragma unroll
  for (int nt = 0; nt < 8; ++nt) {
    float bv = b2[nt * 16 + md];
#pragma unroll
    for (int r = 0; r < 4; ++r) {
      int row = m0 + 16 * wv + qd * 4 + r;
      if (row < N) out[(size_t)row * 128 + nt * 16 + md] = acc[nt][r] + bv;
    }
  }
}

// ---------------- launch ----------------
extern "C" void kernel_launch(void* const* d_in, const int* in_sizes, int n_in,
                              void* d_out, int out_size, void* d_ws, size_t ws_size,
                              hipStream_t stream) {
  const float* x  = (const float*)d_in[0];
  const int*   ei = (const int*)d_in[1];
  const float* W1 = (const float*)d_in[2];
  const float* b1 = (const float*)d_in[3];
  const float* W2 = (const float*)d_in[4];
  const float* b2 = (const float*)d_in[5];
  const int N = in_sizes[0] / 256;
  const int E = in_sizes[1] / 2;
  const int nbS = (N + 511) >> 9;   // src buckets (98; <=128)
  const int nbD = (N + 127) >> 7;   // dst buckets (391; <=512)

  u32 sk1a, sk1b, sk2a, sk2b;
  tf2x32(0u, 42u, 0u, 0u, sk1a, sk1b);
  tf2x32(0u, 42u, 0u, 1u, sk2a, sk2b);

  char* p = (char*)d_ws;
  auto alloc = [&](size_t bytes) { char* r = p; p += (bytes + 255) & ~(size_t)255; return r; };
  // --- zero-init group (contiguous) ---
  int* dstCnt      = (int*)alloc((size_t)512 * CPAD * 4);   // padded: 1 counter / 64B line
  int* srcCnt      = (int*)alloc((size_t)128 * CPAD * 4);   // padded
  int* hcbA        = (int*)alloc((size_t)(1 + HMAX) * 4);
  int* hcbB        = (int*)alloc((size_t)(1 + HMAX) * 4);
  int* outdegB     = (int*)alloc((size_t)nbS * 512 * 4);
  int* dropCnt     = (int*)alloc(256);
  char* zero_end = p;
  // --- rest ---
  u32* dropList = (u32*)alloc((size_t)DROP_CAP * 4);
  u32* idAB     = (u32*)alloc((size_t)nbS * 512 * 4);
  u16* h1b      = (u16*)alloc((size_t)N * 64 * 2);
  u16* hnb      = (u16*)alloc((size_t)N * 64 * 2);
  u16* agg2b    = (u16*)alloc((size_t)N * 64 * 2);
  float* dinv1  = (float*)alloc((size_t)N * 4);
  float* dinv2  = (float*)alloc((size_t)N * 4);
  int* dptr     = (int*)alloc((size_t)(N + 1) * 4);
  int* bucketBase = (int*)alloc(513 * 4);
  u32* entries  = (u32*)alloc((size_t)E * 4);
  u32* srcRec   = (u32*)alloc((size_t)nbS * SB_CAP * 4);
  u64* dstRec   = (u64*)alloc((size_t)nbD * DB_CAP * 8);
  u64* bukA     = (u64*)alloc((size_t)HMAX * MAXD * 8);
  u64* bukB     = (u64*)alloc((size_t)HMAX * MAXD * 8);
  u16* W2t      = (u16*)alloc(64 * 128 * 2);

  int* hcA = hcbA; int* bcA = hcbA + 1;
  int* hcB = hcbB; int* bcB = hcbB + 1;

  hipMemsetAsync(dstCnt, 0x00, (size_t)(zero_end - (char*)dstCnt), stream);

  const int nBin = (E + SBCHUNK - 1) / SBCHUNK;
  const int nGemm = (N + 63) / 64;
  k_mega1<<<nBin + nGemm + 1, 256, 0, stream>>>(ei, E, x, N, W1, W2,
                                                srcCnt, srcRec, dstCnt, dstRec, h1b, W2t, nBin);
  k_shist<<<nbS * SPLIT, 256, 0, stream>>>(srcCnt, srcRec, outdegB);
  k_hdetect<<<(N + 255) / 256, 256, 0, stream>>>(outdegB, idAB, hcA, hcB, dstCnt, bucketBase,
                                                 dptr, nbD, N);
  k_hfill<<<nbS * SPLIT, 256, 0, stream>>>(srcCnt, srcRec, idAB, bcA, bukA, bcB, bukB,
                                           sk1a, sk1b, sk2a, sk2b);
  k_rank2<<<HMAX / 2, 256, 0, stream>>>(hcA, bcA, bukA, hcB, bcB, bukB, dropCnt, dropList);
  k_phase2<<<nbD, 256, 0, stream>>>(bucketBase, dstCnt, dstRec, dropCnt, dropList,
                                    entries, dptr, dinv1, dinv2, N);
  k_conv1n<<<(N * 64 + 255) / 256, 256, 0, stream>>>(dptr, entries, dinv1, (const uint4*)h1b, b1,
                                                     (uint4*)hnb, N);
  k_agg2<<<(N * 64 + 255) / 256, 256, 0, stream>>>(dptr, entries, dinv2, (const uint4*)hnb,
                                                   (uint4*)agg2b, N);
  k_gemm2f<<<(N + 63) / 64, 256, 0, stream>>>(agg2b, W2t, b2, (float*)d_out, N);
}

// Round 12
// 259.350 us; speedup vs baseline: 1.0131x; 1.0131x over previous
//
#include <hip/hip_runtime.h>

typedef unsigned int u32;
typedef unsigned short u16;
typedef unsigned long long u64;
typedef __attribute__((ext_vector_type(8))) short bh8;   // 8 bf16 (4 VGPRs) MFMA frag
typedef __attribute__((ext_vector_type(4))) float f4;    // 4 fp32 acc

#define HMAX 1024    // max heavy (deg>S) nodes tracked; expected ~65
#define MAXD 128     // max out-degree bucketed; expected max ~58
#define SB_CAP 24576 // src-bin capacity: mean 16384, sigma ~127 -> +64 sigma
#define DB_CAP 6144  // dst-bin capacity: mean 4092, sigma ~64 -> +32 sigma
#define SBCHUNK 8192 // edges per bin block (2 sorted halves of 4096)
#define SPLIT 8      // blocks per src bucket in shist/hfill
#define G1S 72       // gemm1 LDS row stride (64 + 8 pad)
#define DROP_CAP 32768
#define CPAD 16      // pad contended global counters to one per 64B line

__device__ inline f4 mfma16(bh8 a, bh8 b, f4 c) {
  return __builtin_amdgcn_mfma_f32_16x16x32_bf16(a, b, c, 0, 0, 0);
}

// ---------------- threefry2x32 (exact JAX cipher) ----------------
__host__ __device__ inline void tf2x32(u32 k0, u32 k1, u32 x0, u32 x1, u32& o0, u32& o1) {
  u32 ks2 = k0 ^ k1 ^ 0x1BD11BDAu;
#define ROTL32(x,d) (((x)<<(d))|((x)>>(32-(d))))
#define TFR(r) { x0 += x1; x1 = ROTL32(x1,(r)); x1 ^= x0; }
  x0 += k0; x1 += k1;
  TFR(13) TFR(15) TFR(26) TFR(6)
  x0 += k1; x1 += ks2 + 1u;
  TFR(17) TFR(29) TFR(16) TFR(24)
  x0 += ks2; x1 += k0 + 2u;
  TFR(13) TFR(15) TFR(26) TFR(6)
  x0 += k0; x1 += k1 + 3u;
  TFR(17) TFR(29) TFR(16) TFR(24)
  x0 += k1; x1 += ks2 + 4u;
  TFR(13) TFR(15) TFR(26) TFR(6)
  x0 += ks2; x1 += k0 + 5u;
  o0 = x0; o1 = x1;
#undef TFR
#undef ROTL32
}

__device__ inline u16 f2bf(float f) {      // round-to-nearest-even (finite inputs)
  u32 u = __float_as_uint(f);
  return (u16)((u + 0x7FFFu + ((u >> 16) & 1u)) >> 16);
}
__device__ inline float bflo(u32 u) { return __uint_as_float(u << 16); }
__device__ inline float bfhi(u32 u) { return __uint_as_float(u & 0xFFFF0000u); }

// NOTE: parameter named 'wt' (NOT 'w') so member selectors .x/.y/.z/.w don't get captured
#define ACC8(uv, wt) \
  a0 = fmaf(wt, bflo(uv.x), a0); a1 = fmaf(wt, bfhi(uv.x), a1); \
  a2 = fmaf(wt, bflo(uv.y), a2); a3 = fmaf(wt, bfhi(uv.y), a3); \
  a4 = fmaf(wt, bflo(uv.z), a4); a5 = fmaf(wt, bfhi(uv.z), a5); \
  a6 = fmaf(wt, bflo(uv.w), a6); a7 = fmaf(wt, bfhi(uv.w), a7);

// depth-4 gather burst: issue up to 4 predicated row loads, then consume.
// (branches are wave-uniform: nq is identical across the wave)
#define GATHER_BURST4(TBL, BASEOFF) \
    { \
      float w0 = __shfl(wgt, grp + (BASEOFF), 64); int s0 = __shfl(s, grp + (BASEOFF), 64); \
      uint4 u0 = TBL[(size_t)s0 * 8 + lo8]; \
      float w1 = 0.f, w2 = 0.f, w3 = 0.f; uint4 u1 = u0, u2 = u0, u3 = u0; \
      if (nq > (BASEOFF)/8 + 1) { w1 = __shfl(wgt, grp + (BASEOFF) + 8, 64);  int s1 = __shfl(s, grp + (BASEOFF) + 8, 64);  u1 = TBL[(size_t)s1 * 8 + lo8]; } \
      if (nq > (BASEOFF)/8 + 2) { w2 = __shfl(wgt, grp + (BASEOFF) + 16, 64); int s2 = __shfl(s, grp + (BASEOFF) + 16, 64); u2 = TBL[(size_t)s2 * 8 + lo8]; } \
      if (nq > (BASEOFF)/8 + 3) { w3 = __shfl(wgt, grp + (BASEOFF) + 24, 64); int s3 = __shfl(s, grp + (BASEOFF) + 24, 64); u3 = TBL[(size_t)s3 * 8 + lo8]; } \
      ACC8(u0, w0) \
      if (nq > (BASEOFF)/8 + 1) { ACC8(u1, w1) } \
      if (nq > (BASEOFF)/8 + 2) { ACC8(u2, w2) } \
      if (nq > (BASEOFF)/8 + 3) { ACC8(u3, w3) } \
    }

// ---------------- mega1: [bin blocks] || [gemm1 blocks] || [W2 prep block] ----------------
// bin path R12: dstRec records counting-sorted in LDS per 4096-edge half -> coalesced copy-out
struct BinS2 {
  u32 lsrc[128]; u32 lbase[128];   // src hist/cursor + global base
  u32 ldst[512]; u32 dbase[512];   // dst hist + global base
  u32 lstart[512]; u32 cur[512];   // LDS exclusive prefix + scatter cursor
  u64 stage[4096];                 // sorted staging (32KB)
};
struct GemS { u16 xs[64 * G1S]; u16 ws[64 * G1S]; };
#define SMEM_BYTES ((sizeof(BinS2) > sizeof(GemS)) ? sizeof(BinS2) : sizeof(GemS))

__global__ __launch_bounds__(256) void k_mega1(const int* __restrict__ ei, int E,
                                               const float* __restrict__ x, int N,
                                               const float* __restrict__ W1, const float* __restrict__ W2,
                                               int* __restrict__ srcCnt, u32* __restrict__ srcRec,
                                               int* __restrict__ dstCnt, u64* __restrict__ dstRec,
                                               u16* __restrict__ h1b, u16* __restrict__ W2t, int nBin) {
  __shared__ __align__(16) char smem[SMEM_BYTES];
  int t = threadIdx.x;
  int bid = blockIdx.x;
  int nGemm = (N + 63) >> 6;

  if (bid < nBin) {
    // ---- bin path: per half: hist -> reserve -> LDS-sort -> coalesced copy ----
    BinS2& S = *(BinS2*)smem;
    int lo = bid * SBCHUNK;
    int hi = min(lo + SBCHUNK, E);
    bool fast = ((E & 3) == 0);

    auto loadE = [&](int e0, int nv, int* sv, int* dv) {
      if (nv == 8 && fast) {
        int4 a0 = *((const int4*)(ei + e0));
        int4 a1 = *((const int4*)(ei + e0 + 4));
        int4 b0 = *((const int4*)(ei + E + e0));
        int4 b1 = *((const int4*)(ei + E + e0 + 4));
        sv[0]=a0.x; sv[1]=a0.y; sv[2]=a0.z; sv[3]=a0.w; sv[4]=a1.x; sv[5]=a1.y; sv[6]=a1.z; sv[7]=a1.w;
        dv[0]=b0.x; dv[1]=b0.y; dv[2]=b0.z; dv[3]=b0.w; dv[4]=b1.x; dv[5]=b1.y; dv[6]=b1.z; dv[7]=b1.w;
      } else {
        for (int j = 0; j < nv; ++j) { sv[j] = ei[e0 + j]; dv[j] = ei[E + e0 + j]; }
      }
    };

    for (int h = 0; h < 2; ++h) {
      int hlo = lo + h * 4096;
      if (hlo >= hi) break;
      int hhi = min(hlo + 4096, hi);
      if (t < 128) S.lsrc[t] = 0;
      for (int v = t; v < 512; v += 256) S.ldst[v] = 0;
      __syncthreads();
      // pass 1: histograms
      for (int sub = 0; sub < 4096; sub += 2048) {
        int e0 = hlo + sub + 8 * t;
        int nv = min(8, hhi - e0); if (nv < 0) nv = 0;
        int sv[8], dv[8];
        loadE(e0, nv, sv, dv);
        for (int j = 0; j < nv; ++j) {
          atomicAdd(&S.lsrc[sv[j] >> 9], 1u);
          atomicAdd(&S.ldst[dv[j] >> 7], 1u);
        }
      }
      __syncthreads();
      // pass 2: reserve global bases (padded counters)
      if (t < 128) {
        u32 c = S.lsrc[t];
        if (c) S.lbase[t] = (u32)atomicAdd(&srcCnt[t * CPAD], (int)c);
        S.lsrc[t] = 0;
      }
      for (int v = t; v < 512; v += 256) {
        u32 cd = S.ldst[v];
        if (cd) S.dbase[v] = (u32)atomicAdd(&dstCnt[v * CPAD], (int)cd);
      }
      // inclusive prefix scan of ldst (ping-pong lstart <-> cur, 9 steps -> result in cur)
      for (int v = t; v < 512; v += 256) S.lstart[v] = S.ldst[v];
      __syncthreads();
      {
        u32* sb = S.lstart; u32* db = S.cur;
        for (int off = 1; off < 512; off <<= 1) {
          for (int v = t; v < 512; v += 256)
            db[v] = sb[v] + ((v >= off) ? sb[v - off] : 0u);
          __syncthreads();
          u32* tmp = sb; sb = db; db = tmp;
        }
      }
      int tot = (int)S.cur[511];               // inclusive total (9 steps end in cur)
      __syncthreads();
      for (int v = t; v < 512; v += 256) S.lstart[v] = (v == 0) ? 0u : S.cur[v - 1];
      __syncthreads();
      for (int v = t; v < 512; v += 256) S.cur[v] = S.lstart[v];
      __syncthreads();
      // pass 3: reload edges; src direct scatter, dst -> LDS stage (bucket in bits 45+)
      for (int sub = 0; sub < 4096; sub += 2048) {
        int e0 = hlo + sub + 8 * t;
        int nv = min(8, hhi - e0); if (nv < 0) nv = 0;
        int sv[8], dv[8];
        loadE(e0, nv, sv, dv);
        for (int j = 0; j < nv; ++j) {
          int s = sv[j], d = dv[j];
          u32 i = (u32)(e0 + j);
          int bs = s >> 9;
          u32 slot = S.lbase[bs] + atomicAdd(&S.lsrc[bs], 1u);
          if (slot < SB_CAP) srcRec[(size_t)bs * SB_CAP + slot] = ((u32)(s & 511) << 21) | i;
          int bd = d >> 7;
          u32 r = atomicAdd(&S.cur[bd], 1u);
          S.stage[r] = ((u64)(u32)bd << 45) | ((u64)(d & 127) << 37) | ((u64)(u32)s << 21) | i;
        }
      }
      __syncthreads();
      // pass 4: coalesced copy-out (consecutive i -> same bucket, consecutive slots)
      for (int i2 = t; i2 < tot; i2 += 256) {
        u64 rec = S.stage[i2];
        u32 bd = (u32)(rec >> 45) & 511u;
        u32 gslot = S.dbase[bd] + ((u32)i2 - S.lstart[bd]);
        if (gslot < DB_CAP)
          dstRec[(size_t)bd * DB_CAP + gslot] = rec & 0x1FFFFFFFFFFFULL;
      }
      __syncthreads();
    }
  } else if (bid < nBin + nGemm) {
    // ---- gemm1 path: h1 = bf16(x) @ bf16(W1), K-tile 64 ----
    GemS& G = *(GemS*)smem;
    int wv = t >> 6, lane = t & 63;
    int qd = lane >> 4, md = lane & 15;
    int m0 = (bid - nBin) * 64;
    if (m0 >= N) return;
    f4 acc[4] = {};
    for (int ks = 0; ks < 256; ks += 64) {
      __syncthreads();
#pragma unroll
      for (int i = 0; i < 4; ++i) {             // stage x[m0..+63][ks..+63] -> bf16 LDS (1024 float4)
        int f = t + 256 * i;
        int r = f >> 4, c4 = f & 15;
        int grow = m0 + r; if (grow >= N) grow = N - 1;
        float4 v = ((const float4*)x)[(size_t)grow * 64 + (ks >> 2) + c4];
        u32 p0 = (u32)f2bf(v.x) | ((u32)f2bf(v.y) << 16);
        u32 p1 = (u32)f2bf(v.z) | ((u32)f2bf(v.w) << 16);
        *((uint2*)(G.xs + r * G1S + c4 * 4)) = make_uint2(p0, p1);
      }
#pragma unroll
      for (int i = 0; i < 4; ++i) {             // stage W1[ks..+63][0..63] fp32 -> bf16 n-major
        int f = t + 256 * i;
        int k = f >> 4, c4 = f & 15;
        float4 v = ((const float4*)W1)[(ks + k) * 16 + c4];
        int n0 = c4 * 4;
        G.ws[(n0 + 0) * G1S + k] = f2bf(v.x);
        G.ws[(n0 + 1) * G1S + k] = f2bf(v.y);
        G.ws[(n0 + 2) * G1S + k] = f2bf(v.z);
        G.ws[(n0 + 3) * G1S + k] = f2bf(v.w);
      }
      __syncthreads();
#pragma unroll
      for (int kk = 0; kk < 64; kk += 32) {
        bh8 af = *((const bh8*)(G.xs + (16 * wv + md) * G1S + kk + qd * 8));
#pragma unroll
        for (int nt = 0; nt < 4; ++nt) {
          bh8 bf = *((const bh8*)(G.ws + (nt * 16 + md) * G1S + kk + qd * 8));
          acc[nt] = mfma16(af, bf, acc[nt]);
        }
      }
    }
#pragma unroll
    for (int nt = 0; nt < 4; ++nt)
#pragma unroll
      for (int r = 0; r < 4; ++r) {
        int row = m0 + 16 * wv + qd * 4 + r;
        if (row < N) h1b[(size_t)row * 64 + nt * 16 + md] = f2bf(acc[nt][r]);
      }
  } else {
    // ---- W2 prep path: W2t[n][k] = bf16(W2[k][n]) ----
    for (int e = t; e < 64 * 128; e += 256) {
      int n = e & 127, k = e >> 7;
      W2t[n * 64 + k] = f2bf(W2[k * 128 + n]);
    }
  }
}

// ---------------- shist: partial LDS histograms -> global outdegB ----------------
__global__ __launch_bounds__(256) void k_shist(const int* __restrict__ srcCnt, const u32* __restrict__ srcRec,
                                               int* __restrict__ outdegB) {
  int bk = blockIdx.x >> 3;          // / SPLIT
  int part = blockIdx.x & (SPLIT - 1);
  int total = min(srcCnt[bk * CPAD], SB_CAP);
  int lo = total * part / SPLIT;
  int hi = total * (part + 1) / SPLIT;
  __shared__ u32 cnt[512];
  int t = threadIdx.x;
  cnt[t] = 0; cnt[t + 256] = 0;
  __syncthreads();
  const u32* R = srcRec + (size_t)bk * SB_CAP;
  for (int i = lo + t; i < hi; i += 256) atomicAdd(&cnt[R[i] >> 21], 1u);
  __syncthreads();
  int base = bk * 512;
  for (int v = t; v < 512; v += 256) {
    u32 c = cnt[v];
    if (c) atomicAdd(&outdegB[base + v], (int)c);
  }
}

// ---------------- hdetect: heavy-id assignment + dst-bucket scan (parallel) ----------------
__global__ __launch_bounds__(256) void k_hdetect(const int* __restrict__ outdegB, u32* __restrict__ idAB,
                                                 int* __restrict__ hcA, int* __restrict__ hcB,
                                                 const int* __restrict__ dstCnt, int* __restrict__ bucketBase,
                                                 int* __restrict__ dptr, int nbD, int N) {
  int t = threadIdx.x;
  if (blockIdx.x == 0) {
    __shared__ int sc[512], tp[512];
    for (int i = t; i < 512; i += 256) sc[i] = (i < nbD) ? min(dstCnt[i * CPAD], DB_CAP) : 0;
    __syncthreads();
    for (int off = 1; off < 512; off <<= 1) {
      for (int i = t; i < 512; i += 256) tp[i] = sc[i] + ((i >= off) ? sc[i - off] : 0);
      __syncthreads();
      for (int i = t; i < 512; i += 256) sc[i] = tp[i];
      __syncthreads();
    }
    for (int i = t; i < 512; i += 256) {
      if (i < nbD) bucketBase[i] = (i == 0) ? 0 : sc[i - 1];
    }
    if (t == 0) {
      int tot = sc[nbD - 1];
      bucketBase[nbD] = tot;
      dptr[N] = tot;   // == E (absent overflow)
    }
  }
  int v = blockIdx.x * 256 + t;
  if (v >= N) return;
  int dg = outdegB[v];
  u32 pk = 0;
  if (dg > 50) {
    int idb = atomicAdd(hcB, 1);
    if (idb < HMAX) pk = (u32)(idb + 1);
    if (dg > 100) {
      int ida = atomicAdd(hcA, 1);
      if (ida < HMAX) pk |= (u32)(ida + 1) << 16;
    }
  }
  idAB[v] = pk;
}

// ---------------- hfill: PRNG-bucket heavy edges ----------------
__global__ __launch_bounds__(256) void k_hfill(const int* __restrict__ srcCnt, const u32* __restrict__ srcRec,
                                               const u32* __restrict__ idAB,
                                               int* __restrict__ bcA, u64* __restrict__ bukA,
                                               int* __restrict__ bcB, u64* __restrict__ bukB,
                                               u32 kaA, u32 kbA, u32 kaB, u32 kbB) {
  int bk = blockIdx.x >> 3;
  int part = blockIdx.x & (SPLIT - 1);
  int total = min(srcCnt[bk * CPAD], SB_CAP);
  int lo = total * part / SPLIT;
  int hi = total * (part + 1) / SPLIT;
  const u32* R = srcRec + (size_t)bk * SB_CAP;
  int base = bk * 512;
  for (int i = lo + threadIdx.x; i < hi; i += 256) {
    u32 r = R[i];
    u32 pk = idAB[base + (int)(r >> 21)];
    if (pk) {
      u32 e = r & 0x1FFFFFu;
      int idb = (int)(pk & 0xFFFFu) - 1;
      if (idb >= 0) {
        u32 w0, w1; tf2x32(kaB, kbB, 0u, e, w0, w1);
        int slot = atomicAdd(&bcB[idb], 1);
        if (slot < MAXD) bukB[(size_t)idb * MAXD + slot] = ((u64)((w0 ^ w1) >> 9) << 32) | e;
      }
      int ida = (int)(pk >> 16) - 1;
      if (ida >= 0) {
        u32 w0, w1; tf2x32(kaA, kbA, 0u, e, w0, w1);
        int slot = atomicAdd(&bcA[ida], 1);
        if (slot < MAXD) bukA[(size_t)ida * MAXD + slot] = ((u64)((w0 ^ w1) >> 9) << 32) | e;
      }
    }
  }
}

// ---------------- rank2: drop rank >= S -> append (eid | bit<<21) to dropList ----------------
__global__ __launch_bounds__(256) void k_rank2(const int* __restrict__ hcA, const int* __restrict__ bcA,
                                               const u64* __restrict__ bukA,
                                               const int* __restrict__ hcB, const int* __restrict__ bcB,
                                               const u64* __restrict__ bukB,
                                               int* __restrict__ dropCnt, u32* __restrict__ dropList) {
  bool isA = blockIdx.x < (HMAX / 4);
  int bx = isA ? blockIdx.x : blockIdx.x - HMAX / 4;
  const int* hcount = isA ? hcA : hcB;
  const int* bcount = isA ? bcA : bcB;
  const u64* bucket = isA ? bukA : bukB;
  int S = isA ? 100 : 50;
  u32 bit = isA ? 1u : 2u;
  int wid = (bx * 256 + (int)threadIdx.x) >> 6;
  int lane = threadIdx.x & 63;
  int hc = hcount[0]; if (hc > HMAX) hc = HMAX;
  if (wid >= hc) return;
  int d = bcount[wid]; if (d > MAXD) d = MAXD;
  const u64* B = bucket + (size_t)wid * MAXD;
  for (int i = lane; i < d; i += 64) {
    u64 ki = B[i];
    int rank = 0;
    for (int j = 0; j < d; ++j) rank += (B[j] < ki) ? 1 : 0;
    if (rank >= S) {
      int idx = atomicAdd(dropCnt, 1);
      if (idx < DROP_CAP) dropList[idx] = ((u32)ki & 0x1FFFFFu) | (bit << 21);
    }
  }
}

// ---------------- phase2: per-bucket counting sort from dstRec -> entries/dptr/dinv ----------------
// dstRec = dstlow7(37:44) | src(21:36) | eid(0:20); single global pass, pass-2 from LDS cache
__global__ __launch_bounds__(256) void k_phase2(const int* __restrict__ bucketBase,
                                                const int* __restrict__ dstCnt,
                                                const u64* __restrict__ dstRec,
                                                const int* __restrict__ dropCnt,
                                                const u32* __restrict__ dropList,
                                                u32* __restrict__ entries, int* __restrict__ dptr,
                                                float* __restrict__ dinv1, float* __restrict__ dinv2, int N) {
  int b = blockIdx.x;
  int base = bucketBase[b];
  int cnt0 = min(dstCnt[b * CPAD], DB_CAP);
  const u64* R = dstRec + (size_t)b * DB_CAP;
  __shared__ u32 cnt[128];
  __shared__ u32 htab[4096];
  __shared__ u32 ws2[2];
  __shared__ u32 earr[DB_CAP];     // per-edge decode cache: src(0:15)|drop(16:17)|dl(18:24)
  int t = threadIdx.x;
  if (t < 128) cnt[t] = 0;
  for (int i = t; i < 4096; i += 256) htab[i] = 0xFFFFFFFFu;
  __syncthreads();
  int dc = min(dropCnt[0], 3072);
  for (int i = t; i < dc; i += 256) {
    u32 pk = dropList[i];
    u32 key = pk & 0x1FFFFFu;
    u32 h = (key * 2654435761u) >> 20;
    while (true) {
      u32 old = atomicCAS(&htab[h], 0xFFFFFFFFu, pk);
      if (old == 0xFFFFFFFFu) break;
      if ((old & 0x1FFFFFu) == key) { atomicOr(&htab[h], pk & 0x00600000u); break; }
      h = (h + 1) & 4095;
    }
  }
  __syncthreads();
  // pass 1: packed histogram total(0:9) | keep1(10:19) | keep2(20:29); cache decode in LDS
  for (int i = t; i < cnt0; i += 256) {
    u64 r = R[i];
    u32 dl = (u32)(r >> 37) & 127u;
    u32 key = (u32)r & 0x1FFFFFu;
    u32 drop = 0;
    u32 h = (key * 2654435761u) >> 20;
    while (true) {
      u32 v = htab[h];
      if (v == 0xFFFFFFFFu) break;
      if ((v & 0x1FFFFFu) == key) { drop = (v >> 21) & 3u; break; }
      h = (h + 1) & 4095;
    }
    u32 src = (u32)(r >> 21) & 0xFFFFu;
    earr[i] = src | (drop << 16) | (dl << 18);
    u32 add = 1u + ((1u - (drop & 1u)) << 10) + ((1u - ((drop >> 1) & 1u)) << 20);
    atomicAdd(&cnt[dl], add);
  }
  __syncthreads();
  u32 c0 = (t < 128) ? cnt[t] : 0;
  u32 tot = c0 & 1023u;
  int lane = t & 63, w = t >> 6;
  u32 incl = tot;
  for (int off = 1; off < 64; off <<= 1) {
    u32 nbv = (u32)__shfl_up((int)incl, off, 64);
    if (lane >= off) incl += nbv;
  }
  if (lane == 63 && w == 0) ws2[0] = incl;
  __syncthreads();
  u32 excl = incl - tot + ((w == 1) ? ws2[0] : 0u);
  int v0 = b * 128 + t;
  if (t < 128 && v0 < N) {
    dptr[v0] = base + (int)excl;
    dinv1[v0] = 1.0f / sqrtf((float)(((c0 >> 10) & 1023u) + 1u));
    dinv2[v0] = 1.0f / sqrtf((float)(((c0 >> 20) & 1023u) + 1u));
  }
  __syncthreads();
  if (t < 128) cnt[t] = excl;
  __syncthreads();
  // pass 2: scatter from LDS cache (no dstRec re-read, no re-probe)
  for (int i = t; i < cnt0; i += 256) {
    u32 p = earr[i];
    u32 dl = (p >> 18) & 127u;
    u32 drop = (p >> 16) & 3u;
    u32 src = p & 0xFFFFu;
    u32 slot = atomicAdd(&cnt[dl], 1u);
    entries[base + slot] = src | ((drop & 1u) ? 0u : (1u << 30)) | ((drop & 2u) ? 0u : (1u << 31));
  }
}

// ---------------- conv1: aggregate h1 + bias + relu + L2 normalize -> bf16 hnb ----------------
// wave per dst; eighth-wave: 8 lanes x uint4 = 128B row; depth-4 gather bursts (R10 best)
__global__ __launch_bounds__(256) void k_conv1n(const int* __restrict__ ptr, const u32* __restrict__ entries,
                                                const float* __restrict__ dinv1, const uint4* __restrict__ h1q,
                                                const float* __restrict__ b1, uint4* __restrict__ hnbq, int N) {
  int wid = (blockIdx.x * 256 + threadIdx.x) >> 6;
  if (wid >= N) return;
  int lane = threadIdx.x & 63;
  int lo8 = lane & 7, grp = lane >> 3;
  int beg = ptr[wid], end = ptr[wid + 1];
  float a0 = 0.f, a1 = 0.f, a2 = 0.f, a3 = 0.f, a4 = 0.f, a5 = 0.f, a6 = 0.f, a7 = 0.f;
  for (int cb = beg; cb < end; cb += 64) {
    int idx = cb + lane;
    float wgt = 0.f; int s = 0;
    if (idx < end) {
      u32 e = entries[idx];
      s = (int)(e & 0xFFFFu);
      if (e & (1u << 30)) wgt = dinv1[s];
    }
    int nq = (min(64, end - cb) + 7) >> 3;
    GATHER_BURST4(h1q, 0)
    if (nq > 4) { GATHER_BURST4(h1q, 32) }
  }
#pragma unroll
  for (int off = 8; off < 64; off <<= 1) {
    a0 += __shfl_xor(a0, off, 64); a1 += __shfl_xor(a1, off, 64);
    a2 += __shfl_xor(a2, off, 64); a3 += __shfl_xor(a3, off, 64);
    a4 += __shfl_xor(a4, off, 64); a5 += __shfl_xor(a5, off, 64);
    a6 += __shfl_xor(a6, off, 64); a7 += __shfl_xor(a7, off, 64);
  }
  float dv = dinv1[wid];
  uint4 uo = h1q[(size_t)wid * 8 + lo8];
  a0 = fmaf(dv, bflo(uo.x), a0); a1 = fmaf(dv, bfhi(uo.x), a1);
  a2 = fmaf(dv, bflo(uo.y), a2); a3 = fmaf(dv, bfhi(uo.y), a3);
  a4 = fmaf(dv, bflo(uo.z), a4); a5 = fmaf(dv, bfhi(uo.z), a5);
  a6 = fmaf(dv, bflo(uo.w), a6); a7 = fmaf(dv, bfhi(uo.w), a7);
  float4 bbA = ((const float4*)b1)[lo8 * 2];
  float4 bbB = ((const float4*)b1)[lo8 * 2 + 1];
  float o0 = fmaxf(fmaf(dv, a0, bbA.x), 0.f);
  float o1 = fmaxf(fmaf(dv, a1, bbA.y), 0.f);
  float o2 = fmaxf(fmaf(dv, a2, bbA.z), 0.f);
  float o3 = fmaxf(fmaf(dv, a3, bbA.w), 0.f);
  float o4 = fmaxf(fmaf(dv, a4, bbB.x), 0.f);
  float o5 = fmaxf(fmaf(dv, a5, bbB.y), 0.f);
  float o6 = fmaxf(fmaf(dv, a6, bbB.z), 0.f);
  float o7 = fmaxf(fmaf(dv, a7, bbB.w), 0.f);
  float ss = fmaf(o0, o0, fmaf(o1, o1, fmaf(o2, o2, o3 * o3)))
           + fmaf(o4, o4, fmaf(o5, o5, fmaf(o6, o6, o7 * o7)));
#pragma unroll
  for (int off = 1; off < 8; off <<= 1) ss += __shfl_xor(ss, off, 8);
  float sc = 1.f / fmaxf(sqrtf(ss), 1e-12f);
  if (lane < 8) {
    uint4 pv;
    pv.x = (u32)f2bf(o0 * sc) | ((u32)f2bf(o1 * sc) << 16);
    pv.y = (u32)f2bf(o2 * sc) | ((u32)f2bf(o3 * sc) << 16);
    pv.z = (u32)f2bf(o4 * sc) | ((u32)f2bf(o5 * sc) << 16);
    pv.w = (u32)f2bf(o6 * sc) | ((u32)f2bf(o7 * sc) << 16);
    hnbq[(size_t)wid * 8 + lo8] = pv;
  }
}

// ---------------- agg2: aggregate hnb with dinv2 -> bf16 agg2b (depth-4 bursts) ----------------
__global__ __launch_bounds__(256) void k_agg2(const int* __restrict__ ptr, const u32* __restrict__ entries,
                                              const float* __restrict__ dinv2, const uint4* __restrict__ hnq,
                                              uint4* __restrict__ agg2q, int N) {
  int wid = (blockIdx.x * 256 + threadIdx.x) >> 6;
  if (wid >= N) return;
  int lane = threadIdx.x & 63;
  int lo8 = lane & 7, grp = lane >> 3;
  int beg = ptr[wid], end = ptr[wid + 1];
  float a0 = 0.f, a1 = 0.f, a2 = 0.f, a3 = 0.f, a4 = 0.f, a5 = 0.f, a6 = 0.f, a7 = 0.f;
  for (int cb = beg; cb < end; cb += 64) {
    int idx = cb + lane;
    float wgt = 0.f; int s = 0;
    if (idx < end) {
      u32 e = entries[idx];
      s = (int)(e & 0xFFFFu);
      if (e & (1u << 31)) wgt = dinv2[s];
    }
    int nq = (min(64, end - cb) + 7) >> 3;
    GATHER_BURST4(hnq, 0)
    if (nq > 4) { GATHER_BURST4(hnq, 32) }
  }
#pragma unroll
  for (int off = 8; off < 64; off <<= 1) {
    a0 += __shfl_xor(a0, off, 64); a1 += __shfl_xor(a1, off, 64);
    a2 += __shfl_xor(a2, off, 64); a3 += __shfl_xor(a3, off, 64);
    a4 += __shfl_xor(a4, off, 64); a5 += __shfl_xor(a5, off, 64);
    a6 += __shfl_xor(a6, off, 64); a7 += __shfl_xor(a7, off, 64);
  }
  float dv = dinv2[wid];
  uint4 uo = hnq[(size_t)wid * 8 + lo8];
  a0 = fmaf(dv, bflo(uo.x), a0); a1 = fmaf(dv, bfhi(uo.x), a1);
  a2 = fmaf(dv, bflo(uo.y), a2); a3 = fmaf(dv, bfhi(uo.y), a3);
  a4 = fmaf(dv, bflo(uo.z), a4); a5 = fmaf(dv, bfhi(uo.z), a5);
  a6 = fmaf(dv, bflo(uo.w), a6); a7 = fmaf(dv, bfhi(uo.w), a7);
  if (lane < 8) {
    uint4 pv;
    pv.x = (u32)f2bf(dv * a0) | ((u32)f2bf(dv * a1) << 16);
    pv.y = (u32)f2bf(dv * a2) | ((u32)f2bf(dv * a3) << 16);
    pv.z = (u32)f2bf(dv * a4) | ((u32)f2bf(dv * a5) << 16);
    pv.w = (u32)f2bf(dv * a6) | ((u32)f2bf(dv * a7) << 16);
    agg2q[(size_t)wid * 8 + lo8] = pv;
  }
}

// ---------------- gemm2f: out = agg2b @ W2 + b2 (MFMA, fused bias, fp32 out) ----------------
#define G2S 72
__global__ __launch_bounds__(256) void k_gemm2f(const u16* __restrict__ aggb, const u16* __restrict__ W2t,
                                                const float* __restrict__ b2, float* __restrict__ out, int N) {
  __shared__ u16 hs[64 * G2S];
  __shared__ u16 ws[128 * G2S];
  int t = threadIdx.x;
  int wv = t >> 6, lane = t & 63;
  int qd = lane >> 4, md = lane & 15;
  int m0 = blockIdx.x * 64;
#pragma unroll
  for (int i = 0; i < 2; ++i) {                 // stage aggb: 64 rows x 64 u16 = 512 uint4
    int cc = t + 256 * i;
    int r = cc >> 3, kc = (cc & 7) * 8;
    int grow = m0 + r; if (grow >= N) grow = N - 1;
    *((uint4*)(hs + r * G2S + kc)) = *((const uint4*)(aggb + (size_t)grow * 64 + kc));
  }
#pragma unroll
  for (int i = 0; i < 4; ++i) {                 // stage W2t (128x64 u16)
    int cc = t + 256 * i;
    int n = cc >> 3, kc = (cc & 7) * 8;
    *((uint4*)(ws + n * G2S + kc)) = *((const uint4*)(W2t + n * 64 + kc));
  }
  __syncthreads();
  f4 acc[8] = {};
#pragma unroll
  for (int kk = 0; kk < 64; kk += 32) {
    bh8 af = *((const bh8*)(hs + (16 * wv + md) * G2S + kk + qd * 8));
#pragma unroll
    for (int nt = 0; nt < 8; ++nt) {
      bh8 bf = *((const bh8*)(ws + (nt * 16 + md) * G2S + kk + qd * 8));
      acc[nt] = mfma16(af, bf, acc[nt]);
    }
  }
#pragma unroll
  for (int nt = 0; nt < 8; ++nt) {
    float bv = b2[nt * 16 + md];
#pragma unroll
    for (int r = 0; r < 4; ++r) {
      int row = m0 + 16 * wv + qd * 4 + r;
      if (row < N) out[(size_t)row * 128 + nt * 16 + md] = acc[nt][r] + bv;
    }
  }
}

// ---------------- launch ----------------
extern "C" void kernel_launch(void* const* d_in, const int* in_sizes, int n_in,
                              void* d_out, int out_size, void* d_ws, size_t ws_size,
                              hipStream_t stream) {
  const float* x  = (const float*)d_in[0];
  const int*   ei = (const int*)d_in[1];
  const float* W1 = (const float*)d_in[2];
  const float* b1 = (const float*)d_in[3];
  const float* W2 = (const float*)d_in[4];
  const float* b2 = (const float*)d_in[5];
  const int N = in_sizes[0] / 256;
  const int E = in_sizes[1] / 2;
  const int nbS = (N + 511) >> 9;   // src buckets (98; <=128)
  const int nbD = (N + 127) >> 7;   // dst buckets (391; <=512)

  u32 sk1a, sk1b, sk2a, sk2b;
  tf2x32(0u, 42u, 0u, 0u, sk1a, sk1b);
  tf2x32(0u, 42u, 0u, 1u, sk2a, sk2b);

  char* p = (char*)d_ws;
  auto alloc = [&](size_t bytes) { char* r = p; p += (bytes + 255) & ~(size_t)255; return r; };
  // --- zero-init group (contiguous) ---
  int* dstCnt      = (int*)alloc((size_t)512 * CPAD * 4);   // padded: 1 counter / 64B line
  int* srcCnt      = (int*)alloc((size_t)128 * CPAD * 4);   // padded
  int* hcbA        = (int*)alloc((size_t)(1 + HMAX) * 4);
  int* hcbB        = (int*)alloc((size_t)(1 + HMAX) * 4);
  int* outdegB     = (int*)alloc((size_t)nbS * 512 * 4);
  int* dropCnt     = (int*)alloc(256);
  char* zero_end = p;
  // --- rest ---
  u32* dropList = (u32*)alloc((size_t)DROP_CAP * 4);
  u32* idAB     = (u32*)alloc((size_t)nbS * 512 * 4);
  u16* h1b      = (u16*)alloc((size_t)N * 64 * 2);
  u16* hnb      = (u16*)alloc((size_t)N * 64 * 2);
  u16* agg2b    = (u16*)alloc((size_t)N * 64 * 2);
  float* dinv1  = (float*)alloc((size_t)N * 4);
  float* dinv2  = (float*)alloc((size_t)N * 4);
  int* dptr     = (int*)alloc((size_t)(N + 1) * 4);
  int* bucketBase = (int*)alloc(513 * 4);
  u32* entries  = (u32*)alloc((size_t)E * 4);
  u32* srcRec   = (u32*)alloc((size_t)nbS * SB_CAP * 4);
  u64* dstRec   = (u64*)alloc((size_t)nbD * DB_CAP * 8);
  u64* bukA     = (u64*)alloc((size_t)HMAX * MAXD * 8);
  u64* bukB     = (u64*)alloc((size_t)HMAX * MAXD * 8);
  u16* W2t      = (u16*)alloc(64 * 128 * 2);

  int* hcA = hcbA; int* bcA = hcbA + 1;
  int* hcB = hcbB; int* bcB = hcbB + 1;

  hipMemsetAsync(dstCnt, 0x00, (size_t)(zero_end - (char*)dstCnt), stream);

  const int nBin = (E + SBCHUNK - 1) / SBCHUNK;
  const int nGemm = (N + 63) / 64;
  k_mega1<<<nBin + nGemm + 1, 256, 0, stream>>>(ei, E, x, N, W1, W2,
                                                srcCnt, srcRec, dstCnt, dstRec, h1b, W2t, nBin);
  k_shist<<<nbS * SPLIT, 256, 0, stream>>>(srcCnt, srcRec, outdegB);
  k_hdetect<<<(N + 255) / 256, 256, 0, stream>>>(outdegB, idAB, hcA, hcB, dstCnt, bucketBase,
                                                 dptr, nbD, N);
  k_hfill<<<nbS * SPLIT, 256, 0, stream>>>(srcCnt, srcRec, idAB, bcA, bukA, bcB, bukB,
                                           sk1a, sk1b, sk2a, sk2b);
  k_rank2<<<HMAX / 2, 256, 0, stream>>>(hcA, bcA, bukA, hcB, bcB, bukB, dropCnt, dropList);
  k_phase2<<<nbD, 256, 0, stream>>>(bucketBase, dstCnt, dstRec, dropCnt, dropList,
                                    entries, dptr, dinv1, dinv2, N);
  k_conv1n<<<(N * 64 + 255) / 256, 256, 0, stream>>>(dptr, entries, dinv1, (const uint4*)h1b, b1,
                                                     (uint4*)hnb, N);
  k_agg2<<<(N * 64 + 255) / 256, 256, 0, stream>>>(dptr, entries, dinv2, (const uint4*)hnb,
                                                   (uint4*)agg2b, N);
  k_gemm2f<<<(N + 63) / 64, 256, 0, stream>>>(agg2b, W2t, b2, (float*)d_out, N);
}

// Round 13
// 254.506 us; speedup vs baseline: 1.0324x; 1.0190x over previous
//
#include <hip/hip_runtime.h>

typedef unsigned int u32;
typedef unsigned short u16;
typedef unsigned long long u64;
typedef __attribute__((ext_vector_type(8))) short bh8;   // 8 bf16 (4 VGPRs) MFMA frag
typedef __attribute__((ext_vector_type(4))) float f4;    // 4 fp32 acc

#define HMAX 1024    // max heavy (deg>S) nodes tracked; expected ~65
#define MAXD 128     // max out-degree bucketed; expected max ~58
#define SB_CAP 24576 // src-bin capacity: mean 16384, sigma ~127 -> +64 sigma
#define DB_CAP 6144  // dst-bin capacity: mean 4092, sigma ~64 -> +32 sigma
#define SBCHUNK 8192 // edges per bin block; R8/R12 proved both smaller chunks and LDS-sort are worse
#define SPLIT 8      // blocks per src bucket in shist/hfill
#define G1S 72       // gemm1 LDS row stride (64 + 8 pad) -> 18.4KB block
#define DROP_CAP 32768
#define CPAD 16      // pad contended global counters to one per 64B line

__device__ inline f4 mfma16(bh8 a, bh8 b, f4 c) {
  return __builtin_amdgcn_mfma_f32_16x16x32_bf16(a, b, c, 0, 0, 0);
}

// ---------------- threefry2x32 (exact JAX cipher) ----------------
__host__ __device__ inline void tf2x32(u32 k0, u32 k1, u32 x0, u32 x1, u32& o0, u32& o1) {
  u32 ks2 = k0 ^ k1 ^ 0x1BD11BDAu;
#define ROTL32(x,d) (((x)<<(d))|((x)>>(32-(d))))
#define TFR(r) { x0 += x1; x1 = ROTL32(x1,(r)); x1 ^= x0; }
  x0 += k0; x1 += k1;
  TFR(13) TFR(15) TFR(26) TFR(6)
  x0 += k1; x1 += ks2 + 1u;
  TFR(17) TFR(29) TFR(16) TFR(24)
  x0 += ks2; x1 += k0 + 2u;
  TFR(13) TFR(15) TFR(26) TFR(6)
  x0 += k0; x1 += k1 + 3u;
  TFR(17) TFR(29) TFR(16) TFR(24)
  x0 += k1; x1 += ks2 + 4u;
  TFR(13) TFR(15) TFR(26) TFR(6)
  x0 += ks2; x1 += k0 + 5u;
  o0 = x0; o1 = x1;
#undef TFR
#undef ROTL32
}

__device__ inline u16 f2bf(float f) {      // round-to-nearest-even (finite inputs)
  u32 u = __float_as_uint(f);
  return (u16)((u + 0x7FFFu + ((u >> 16) & 1u)) >> 16);
}
__device__ inline float bflo(u32 u) { return __uint_as_float(u << 16); }
__device__ inline float bfhi(u32 u) { return __uint_as_float(u & 0xFFFF0000u); }

// NOTE: parameter named 'wt' (NOT 'w') so member selectors .x/.y/.z/.w don't get captured
#define ACC8(uv, wt) \
  a0 = fmaf(wt, bflo(uv.x), a0); a1 = fmaf(wt, bfhi(uv.x), a1); \
  a2 = fmaf(wt, bflo(uv.y), a2); a3 = fmaf(wt, bfhi(uv.y), a3); \
  a4 = fmaf(wt, bflo(uv.z), a4); a5 = fmaf(wt, bfhi(uv.z), a5); \
  a6 = fmaf(wt, bflo(uv.w), a6); a7 = fmaf(wt, bfhi(uv.w), a7);

// depth-4 gather burst: issue up to 4 predicated row loads, then consume.
// (branches are wave-uniform: nq is identical across the wave)
#define GATHER_BURST4(TBL, BASEOFF) \
    { \
      float w0 = __shfl(wgt, grp + (BASEOFF), 64); int s0 = __shfl(s, grp + (BASEOFF), 64); \
      uint4 u0 = TBL[(size_t)s0 * 8 + lo8]; \
      float w1 = 0.f, w2 = 0.f, w3 = 0.f; uint4 u1 = u0, u2 = u0, u3 = u0; \
      if (nq > (BASEOFF)/8 + 1) { w1 = __shfl(wgt, grp + (BASEOFF) + 8, 64);  int s1 = __shfl(s, grp + (BASEOFF) + 8, 64);  u1 = TBL[(size_t)s1 * 8 + lo8]; } \
      if (nq > (BASEOFF)/8 + 2) { w2 = __shfl(wgt, grp + (BASEOFF) + 16, 64); int s2 = __shfl(s, grp + (BASEOFF) + 16, 64); u2 = TBL[(size_t)s2 * 8 + lo8]; } \
      if (nq > (BASEOFF)/8 + 3) { w3 = __shfl(wgt, grp + (BASEOFF) + 24, 64); int s3 = __shfl(s, grp + (BASEOFF) + 24, 64); u3 = TBL[(size_t)s3 * 8 + lo8]; } \
      ACC8(u0, w0) \
      if (nq > (BASEOFF)/8 + 1) { ACC8(u1, w1) } \
      if (nq > (BASEOFF)/8 + 2) { ACC8(u2, w2) } \
      if (nq > (BASEOFF)/8 + 3) { ACC8(u3, w3) } \
    }

// ---------------- mega1: [bin blocks] || [gemm1 blocks] || [W2 prep block] ----------------
// src bins: 128 x 512 nodes (outdeg machinery); dst bins: up to 512 x 128 nodes (CSR sort)
struct BinS { u32 lsrc[128]; u32 lbase[128]; u32 ldst[512]; u32 dbase[512]; };
struct GemS { u16 xs[64 * G1S]; u16 ws[64 * G1S]; };

__global__ __launch_bounds__(256) void k_mega1(const int* __restrict__ ei, int E,
                                               const float* __restrict__ x, int N,
                                               const float* __restrict__ W1, const float* __restrict__ W2,
                                               int* __restrict__ srcCnt, u32* __restrict__ srcRec,
                                               int* __restrict__ dstCnt, u64* __restrict__ dstRec,
                                               u16* __restrict__ h1b, u16* __restrict__ W2t, int nBin) {
  __shared__ __align__(16) char smem[sizeof(GemS)];
  int t = threadIdx.x;
  int bid = blockIdx.x;
  int nGemm = (N + 63) >> 6;

  if (bid < nBin) {
    // ---- bin path: src-bin (u32) + dst-bin (u64); two passes over an 8K-edge chunk ----
    BinS& S = *(BinS*)smem;
    if (t < 128) S.lsrc[t] = 0;
    for (int v = t; v < 512; v += 256) S.ldst[v] = 0;
    __syncthreads();
    int lo = bid * SBCHUNK;
    int hi = min(lo + SBCHUNK, E);
    bool fast = ((E & 3) == 0);

    auto loadE = [&](int e0, int nv, int* sv, int* dv) {
      if (nv == 8 && fast) {
        int4 a0 = *((const int4*)(ei + e0));
        int4 a1 = *((const int4*)(ei + e0 + 4));
        int4 b0 = *((const int4*)(ei + E + e0));
        int4 b1 = *((const int4*)(ei + E + e0 + 4));
        sv[0]=a0.x; sv[1]=a0.y; sv[2]=a0.z; sv[3]=a0.w; sv[4]=a1.x; sv[5]=a1.y; sv[6]=a1.z; sv[7]=a1.w;
        dv[0]=b0.x; dv[1]=b0.y; dv[2]=b0.z; dv[3]=b0.w; dv[4]=b1.x; dv[5]=b1.y; dv[6]=b1.z; dv[7]=b1.w;
      } else {
        for (int j = 0; j < nv; ++j) { sv[j] = ei[e0 + j]; dv[j] = ei[E + e0 + j]; }
      }
    };

    // pass 1: LDS histograms (fire-and-forget atomics)
    for (int sub = 0; sub < SBCHUNK; sub += 2048) {
      int e0 = lo + sub + 8 * t;
      int nv = min(8, hi - e0); if (nv < 0) nv = 0;
      int sv[8], dv[8];
      loadE(e0, nv, sv, dv);
      for (int j = 0; j < nv; ++j) {
        atomicAdd(&S.lsrc[sv[j] >> 9], 1u);
        atomicAdd(&S.ldst[dv[j] >> 7], 1u);
      }
    }
    __syncthreads();
    // pass 2: reserve global bases (padded counters: 1 per 64B line)
    if (t < 128) {
      u32 c = S.lsrc[t];
      if (c) S.lbase[t] = (u32)atomicAdd(&srcCnt[t * CPAD], (int)c);
      S.lsrc[t] = 0;
    }
    for (int v = t; v < 512; v += 256) {
      u32 cd = S.ldst[v];
      if (cd) S.dbase[v] = (u32)atomicAdd(&dstCnt[v * CPAD], (int)cd);
      S.ldst[v] = 0;
    }
    __syncthreads();
    // pass 3: re-read edges (L2/L3-hot), scatter to per-bucket records
    for (int sub = 0; sub < SBCHUNK; sub += 2048) {
      int e0 = lo + sub + 8 * t;
      int nv = min(8, hi - e0); if (nv < 0) nv = 0;
      int sv[8], dv[8];
      loadE(e0, nv, sv, dv);
      for (int j = 0; j < nv; ++j) {
        int s = sv[j], d = dv[j];
        u32 i = (u32)(e0 + j);
        int bs = s >> 9;
        u32 slot = S.lbase[bs] + atomicAdd(&S.lsrc[bs], 1u);
        if (slot < SB_CAP) srcRec[(size_t)bs * SB_CAP + slot] = ((u32)(s & 511) << 21) | i;
        int bd = d >> 7;
        u32 slot2 = S.dbase[bd] + atomicAdd(&S.ldst[bd], 1u);
        if (slot2 < DB_CAP)
          dstRec[(size_t)bd * DB_CAP + slot2] = ((u64)(d & 127) << 37) | ((u64)(u32)s << 21) | i;
      }
    }
  } else if (bid < nBin + nGemm) {
    // ---- gemm1 path: h1 = bf16(x) @ bf16(W1), K-tile 64 (18.4KB LDS) ----
    GemS& G = *(GemS*)smem;
    int wv = t >> 6, lane = t & 63;
    int qd = lane >> 4, md = lane & 15;
    int m0 = (bid - nBin) * 64;
    if (m0 >= N) return;
    f4 acc[4] = {};
    for (int ks = 0; ks < 256; ks += 64) {
      __syncthreads();
#pragma unroll
      for (int i = 0; i < 4; ++i) {             // stage x[m0..+63][ks..+63] -> bf16 LDS (1024 float4)
        int f = t + 256 * i;
        int r = f >> 4, c4 = f & 15;
        int grow = m0 + r; if (grow >= N) grow = N - 1;
        float4 v = ((const float4*)x)[(size_t)grow * 64 + (ks >> 2) + c4];
        u32 p0 = (u32)f2bf(v.x) | ((u32)f2bf(v.y) << 16);
        u32 p1 = (u32)f2bf(v.z) | ((u32)f2bf(v.w) << 16);
        *((uint2*)(G.xs + r * G1S + c4 * 4)) = make_uint2(p0, p1);
      }
#pragma unroll
      for (int i = 0; i < 4; ++i) {             // stage W1[ks..+63][0..63] fp32 -> bf16 n-major
        int f = t + 256 * i;
        int k = f >> 4, c4 = f & 15;
        float4 v = ((const float4*)W1)[(ks + k) * 16 + c4];
        int n0 = c4 * 4;
        G.ws[(n0 + 0) * G1S + k] = f2bf(v.x);
        G.ws[(n0 + 1) * G1S + k] = f2bf(v.y);
        G.ws[(n0 + 2) * G1S + k] = f2bf(v.z);
        G.ws[(n0 + 3) * G1S + k] = f2bf(v.w);
      }
      __syncthreads();
#pragma unroll
      for (int kk = 0; kk < 64; kk += 32) {
        bh8 af = *((const bh8*)(G.xs + (16 * wv + md) * G1S + kk + qd * 8));
#pragma unroll
        for (int nt = 0; nt < 4; ++nt) {
          bh8 bf = *((const bh8*)(G.ws + (nt * 16 + md) * G1S + kk + qd * 8));
          acc[nt] = mfma16(af, bf, acc[nt]);
        }
      }
    }
#pragma unroll
    for (int nt = 0; nt < 4; ++nt)
#pragma unroll
      for (int r = 0; r < 4; ++r) {
        int row = m0 + 16 * wv + qd * 4 + r;
        if (row < N) h1b[(size_t)row * 64 + nt * 16 + md] = f2bf(acc[nt][r]);
      }
  } else {
    // ---- W2 prep path: W2t[n][k] = bf16(W2[k][n]) ----
    for (int e = t; e < 64 * 128; e += 256) {
      int n = e & 127, k = e >> 7;
      W2t[n * 64 + k] = f2bf(W2[k * 128 + n]);
    }
  }
}

// ---------------- shist: partial LDS histograms -> global outdegB ----------------
__global__ __launch_bounds__(256) void k_shist(const int* __restrict__ srcCnt, const u32* __restrict__ srcRec,
                                               int* __restrict__ outdegB) {
  int bk = blockIdx.x >> 3;          // / SPLIT
  int part = blockIdx.x & (SPLIT - 1);
  int total = min(srcCnt[bk * CPAD], SB_CAP);
  int lo = total * part / SPLIT;
  int hi = total * (part + 1) / SPLIT;
  __shared__ u32 cnt[512];
  int t = threadIdx.x;
  cnt[t] = 0; cnt[t + 256] = 0;
  __syncthreads();
  const u32* R = srcRec + (size_t)bk * SB_CAP;
  for (int i = lo + t; i < hi; i += 256) atomicAdd(&cnt[R[i] >> 21], 1u);
  __syncthreads();
  int base = bk * 512;
  for (int v = t; v < 512; v += 256) {
    u32 c = cnt[v];
    if (c) atomicAdd(&outdegB[base + v], (int)c);
  }
}

// ---------------- hdetect: heavy-id assignment + dst-bucket scan (parallel) ----------------
__global__ __launch_bounds__(256) void k_hdetect(const int* __restrict__ outdegB, u32* __restrict__ idAB,
                                                 int* __restrict__ hcA, int* __restrict__ hcB,
                                                 const int* __restrict__ dstCnt, int* __restrict__ bucketBase,
                                                 int* __restrict__ dptr, int nbD, int N) {
  int t = threadIdx.x;
  if (blockIdx.x == 0) {
    __shared__ int sc[512], tp[512];
    for (int i = t; i < 512; i += 256) sc[i] = (i < nbD) ? min(dstCnt[i * CPAD], DB_CAP) : 0;
    __syncthreads();
    for (int off = 1; off < 512; off <<= 1) {
      for (int i = t; i < 512; i += 256) tp[i] = sc[i] + ((i >= off) ? sc[i - off] : 0);
      __syncthreads();
      for (int i = t; i < 512; i += 256) sc[i] = tp[i];
      __syncthreads();
    }
    for (int i = t; i < 512; i += 256) {
      if (i < nbD) bucketBase[i] = (i == 0) ? 0 : sc[i - 1];
    }
    if (t == 0) {
      int tot = sc[nbD - 1];
      bucketBase[nbD] = tot;
      dptr[N] = tot;   // == E (absent overflow)
    }
  }
  int v = blockIdx.x * 256 + t;
  if (v >= N) return;
  int dg = outdegB[v];
  u32 pk = 0;
  if (dg > 50) {
    int idb = atomicAdd(hcB, 1);
    if (idb < HMAX) pk = (u32)(idb + 1);
    if (dg > 100) {
      int ida = atomicAdd(hcA, 1);
      if (ida < HMAX) pk |= (u32)(ida + 1) << 16;
    }
  }
  idAB[v] = pk;
}

// ---------------- hfill: PRNG-bucket heavy edges ----------------
__global__ __launch_bounds__(256) void k_hfill(const int* __restrict__ srcCnt, const u32* __restrict__ srcRec,
                                               const u32* __restrict__ idAB,
                                               int* __restrict__ bcA, u64* __restrict__ bukA,
                                               int* __restrict__ bcB, u64* __restrict__ bukB,
                                               u32 kaA, u32 kbA, u32 kaB, u32 kbB) {
  int bk = blockIdx.x >> 3;
  int part = blockIdx.x & (SPLIT - 1);
  int total = min(srcCnt[bk * CPAD], SB_CAP);
  int lo = total * part / SPLIT;
  int hi = total * (part + 1) / SPLIT;
  const u32* R = srcRec + (size_t)bk * SB_CAP;
  int base = bk * 512;
  for (int i = lo + threadIdx.x; i < hi; i += 256) {
    u32 r = R[i];
    u32 pk = idAB[base + (int)(r >> 21)];
    if (pk) {
      u32 e = r & 0x1FFFFFu;
      int idb = (int)(pk & 0xFFFFu) - 1;
      if (idb >= 0) {
        u32 w0, w1; tf2x32(kaB, kbB, 0u, e, w0, w1);
        int slot = atomicAdd(&bcB[idb], 1);
        if (slot < MAXD) bukB[(size_t)idb * MAXD + slot] = ((u64)((w0 ^ w1) >> 9) << 32) | e;
      }
      int ida = (int)(pk >> 16) - 1;
      if (ida >= 0) {
        u32 w0, w1; tf2x32(kaA, kbA, 0u, e, w0, w1);
        int slot = atomicAdd(&bcA[ida], 1);
        if (slot < MAXD) bukA[(size_t)ida * MAXD + slot] = ((u64)((w0 ^ w1) >> 9) << 32) | e;
      }
    }
  }
}

// ---------------- rank2: drop rank >= S -> append (eid | bit<<21) to dropList ----------------
__global__ __launch_bounds__(256) void k_rank2(const int* __restrict__ hcA, const int* __restrict__ bcA,
                                               const u64* __restrict__ bukA,
                                               const int* __restrict__ hcB, const int* __restrict__ bcB,
                                               const u64* __restrict__ bukB,
                                               int* __restrict__ dropCnt, u32* __restrict__ dropList) {
  bool isA = blockIdx.x < (HMAX / 4);
  int bx = isA ? blockIdx.x : blockIdx.x - HMAX / 4;
  const int* hcount = isA ? hcA : hcB;
  const int* bcount = isA ? bcA : bcB;
  const u64* bucket = isA ? bukA : bukB;
  int S = isA ? 100 : 50;
  u32 bit = isA ? 1u : 2u;
  int wid = (bx * 256 + (int)threadIdx.x) >> 6;
  int lane = threadIdx.x & 63;
  int hc = hcount[0]; if (hc > HMAX) hc = HMAX;
  if (wid >= hc) return;
  int d = bcount[wid]; if (d > MAXD) d = MAXD;
  const u64* B = bucket + (size_t)wid * MAXD;
  for (int i = lane; i < d; i += 64) {
    u64 ki = B[i];
    int rank = 0;
    for (int j = 0; j < d; ++j) rank += (B[j] < ki) ? 1 : 0;
    if (rank >= S) {
      int idx = atomicAdd(dropCnt, 1);
      if (idx < DROP_CAP) dropList[idx] = ((u32)ki & 0x1FFFFFu) | (bit << 21);
    }
  }
}

// ---------------- phase2: per-bucket counting sort from dstRec -> entries/dptr/dinv ----------------
// dstRec = dstlow7(37:44) | src(21:36) | eid(0:20); single global pass, pass-2 from LDS cache
__global__ __launch_bounds__(256) void k_phase2(const int* __restrict__ bucketBase,
                                                const int* __restrict__ dstCnt,
                                                const u64* __restrict__ dstRec,
                                                const int* __restrict__ dropCnt,
                                                const u32* __restrict__ dropList,
                                                u32* __restrict__ entries, int* __restrict__ dptr,
                                                float* __restrict__ dinv1, float* __restrict__ dinv2, int N) {
  int b = blockIdx.x;
  int base = bucketBase[b];
  int cnt0 = min(dstCnt[b * CPAD], DB_CAP);
  const u64* R = dstRec + (size_t)b * DB_CAP;
  __shared__ u32 cnt[128];
  __shared__ u32 htab[4096];
  __shared__ u32 ws2[2];
  __shared__ u32 earr[DB_CAP];     // per-edge decode cache: src(0:15)|drop(16:17)|dl(18:24)
  int t = threadIdx.x;
  if (t < 128) cnt[t] = 0;
  for (int i = t; i < 4096; i += 256) htab[i] = 0xFFFFFFFFu;
  __syncthreads();
  int dc = min(dropCnt[0], 3072);
  for (int i = t; i < dc; i += 256) {
    u32 pk = dropList[i];
    u32 key = pk & 0x1FFFFFu;
    u32 h = (key * 2654435761u) >> 20;
    while (true) {
      u32 old = atomicCAS(&htab[h], 0xFFFFFFFFu, pk);
      if (old == 0xFFFFFFFFu) break;
      if ((old & 0x1FFFFFu) == key) { atomicOr(&htab[h], pk & 0x00600000u); break; }
      h = (h + 1) & 4095;
    }
  }
  __syncthreads();
  // pass 1: packed histogram total(0:9) | keep1(10:19) | keep2(20:29); cache decode in LDS
  for (int i = t; i < cnt0; i += 256) {
    u64 r = R[i];
    u32 dl = (u32)(r >> 37) & 127u;
    u32 key = (u32)r & 0x1FFFFFu;
    u32 drop = 0;
    u32 h = (key * 2654435761u) >> 20;
    while (true) {
      u32 v = htab[h];
      if (v == 0xFFFFFFFFu) break;
      if ((v & 0x1FFFFFu) == key) { drop = (v >> 21) & 3u; break; }
      h = (h + 1) & 4095;
    }
    u32 src = (u32)(r >> 21) & 0xFFFFu;
    earr[i] = src | (drop << 16) | (dl << 18);
    u32 add = 1u + ((1u - (drop & 1u)) << 10) + ((1u - ((drop >> 1) & 1u)) << 20);
    atomicAdd(&cnt[dl], add);
  }
  __syncthreads();
  u32 c0 = (t < 128) ? cnt[t] : 0;
  u32 tot = c0 & 1023u;
  int lane = t & 63, w = t >> 6;
  u32 incl = tot;
  for (int off = 1; off < 64; off <<= 1) {
    u32 nbv = (u32)__shfl_up((int)incl, off, 64);
    if (lane >= off) incl += nbv;
  }
  if (lane == 63 && w == 0) ws2[0] = incl;
  __syncthreads();
  u32 excl = incl - tot + ((w == 1) ? ws2[0] : 0u);
  int v0 = b * 128 + t;
  if (t < 128 && v0 < N) {
    dptr[v0] = base + (int)excl;
    dinv1[v0] = 1.0f / sqrtf((float)(((c0 >> 10) & 1023u) + 1u));
    dinv2[v0] = 1.0f / sqrtf((float)(((c0 >> 20) & 1023u) + 1u));
  }
  __syncthreads();
  if (t < 128) cnt[t] = excl;
  __syncthreads();
  // pass 2: scatter from LDS cache (no dstRec re-read, no re-probe)
  for (int i = t; i < cnt0; i += 256) {
    u32 p = earr[i];
    u32 dl = (p >> 18) & 127u;
    u32 drop = (p >> 16) & 3u;
    u32 src = p & 0xFFFFu;
    u32 slot = atomicAdd(&cnt[dl], 1u);
    entries[base + slot] = src | ((drop & 1u) ? 0u : (1u << 30)) | ((drop & 2u) ? 0u : (1u << 31));
  }
}

// ---------------- conv1: aggregate h1 + bias + relu + L2 normalize -> bf16 hnb ----------------
// wave per dst; eighth-wave: 8 lanes x uint4 = 128B row; depth-4 gather bursts (best: R10)
__global__ __launch_bounds__(256) void k_conv1n(const int* __restrict__ ptr, const u32* __restrict__ entries,
                                                const float* __restrict__ dinv1, const uint4* __restrict__ h1q,
                                                const float* __restrict__ b1, uint4* __restrict__ hnbq, int N) {
  int wid = (blockIdx.x * 256 + threadIdx.x) >> 6;
  if (wid >= N) return;
  int lane = threadIdx.x & 63;
  int lo8 = lane & 7, grp = lane >> 3;
  int beg = ptr[wid], end = ptr[wid + 1];
  float a0 = 0.f, a1 = 0.f, a2 = 0.f, a3 = 0.f, a4 = 0.f, a5 = 0.f, a6 = 0.f, a7 = 0.f;
  for (int cb = beg; cb < end; cb += 64) {
    int idx = cb + lane;
    float wgt = 0.f; int s = 0;
    if (idx < end) {
      u32 e = entries[idx];
      s = (int)(e & 0xFFFFu);
      if (e & (1u << 30)) wgt = dinv1[s];
    }
    int nq = (min(64, end - cb) + 7) >> 3;
    GATHER_BURST4(h1q, 0)
    if (nq > 4) { GATHER_BURST4(h1q, 32) }
  }
#pragma unroll
  for (int off = 8; off < 64; off <<= 1) {
    a0 += __shfl_xor(a0, off, 64); a1 += __shfl_xor(a1, off, 64);
    a2 += __shfl_xor(a2, off, 64); a3 += __shfl_xor(a3, off, 64);
    a4 += __shfl_xor(a4, off, 64); a5 += __shfl_xor(a5, off, 64);
    a6 += __shfl_xor(a6, off, 64); a7 += __shfl_xor(a7, off, 64);
  }
  float dv = dinv1[wid];
  uint4 uo = h1q[(size_t)wid * 8 + lo8];
  a0 = fmaf(dv, bflo(uo.x), a0); a1 = fmaf(dv, bfhi(uo.x), a1);
  a2 = fmaf(dv, bflo(uo.y), a2); a3 = fmaf(dv, bfhi(uo.y), a3);
  a4 = fmaf(dv, bflo(uo.z), a4); a5 = fmaf(dv, bfhi(uo.z), a5);
  a6 = fmaf(dv, bflo(uo.w), a6); a7 = fmaf(dv, bfhi(uo.w), a7);
  float4 bbA = ((const float4*)b1)[lo8 * 2];
  float4 bbB = ((const float4*)b1)[lo8 * 2 + 1];
  float o0 = fmaxf(fmaf(dv, a0, bbA.x), 0.f);
  float o1 = fmaxf(fmaf(dv, a1, bbA.y), 0.f);
  float o2 = fmaxf(fmaf(dv, a2, bbA.z), 0.f);
  float o3 = fmaxf(fmaf(dv, a3, bbA.w), 0.f);
  float o4 = fmaxf(fmaf(dv, a4, bbB.x), 0.f);
  float o5 = fmaxf(fmaf(dv, a5, bbB.y), 0.f);
  float o6 = fmaxf(fmaf(dv, a6, bbB.z), 0.f);
  float o7 = fmaxf(fmaf(dv, a7, bbB.w), 0.f);
  float ss = fmaf(o0, o0, fmaf(o1, o1, fmaf(o2, o2, o3 * o3)))
           + fmaf(o4, o4, fmaf(o5, o5, fmaf(o6, o6, o7 * o7)));
#pragma unroll
  for (int off = 1; off < 8; off <<= 1) ss += __shfl_xor(ss, off, 8);
  float sc = 1.f / fmaxf(sqrtf(ss), 1e-12f);
  if (lane < 8) {
    uint4 pv;
    pv.x = (u32)f2bf(o0 * sc) | ((u32)f2bf(o1 * sc) << 16);
    pv.y = (u32)f2bf(o2 * sc) | ((u32)f2bf(o3 * sc) << 16);
    pv.z = (u32)f2bf(o4 * sc) | ((u32)f2bf(o5 * sc) << 16);
    pv.w = (u32)f2bf(o6 * sc) | ((u32)f2bf(o7 * sc) << 16);
    hnbq[(size_t)wid * 8 + lo8] = pv;
  }
}

// ---------------- agg2: aggregate hnb with dinv2 -> bf16 agg2b (depth-4 bursts) ----------------
__global__ __launch_bounds__(256) void k_agg2(const int* __restrict__ ptr, const u32* __restrict__ entries,
                                              const float* __restrict__ dinv2, const uint4* __restrict__ hnq,
                                              uint4* __restrict__ agg2q, int N) {
  int wid = (blockIdx.x * 256 + threadIdx.x) >> 6;
  if (wid >= N) return;
  int lane = threadIdx.x & 63;
  int lo8 = lane & 7, grp = lane >> 3;
  int beg = ptr[wid], end = ptr[wid + 1];
  float a0 = 0.f, a1 = 0.f, a2 = 0.f, a3 = 0.f, a4 = 0.f, a5 = 0.f, a6 = 0.f, a7 = 0.f;
  for (int cb = beg; cb < end; cb += 64) {
    int idx = cb + lane;
    float wgt = 0.f; int s = 0;
    if (idx < end) {
      u32 e = entries[idx];
      s = (int)(e & 0xFFFFu);
      if (e & (1u << 31)) wgt = dinv2[s];
    }
    int nq = (min(64, end - cb) + 7) >> 3;
    GATHER_BURST4(hnq, 0)
    if (nq > 4) { GATHER_BURST4(hnq, 32) }
  }
#pragma unroll
  for (int off = 8; off < 64; off <<= 1) {
    a0 += __shfl_xor(a0, off, 64); a1 += __shfl_xor(a1, off, 64);
    a2 += __shfl_xor(a2, off, 64); a3 += __shfl_xor(a3, off, 64);
    a4 += __shfl_xor(a4, off, 64); a5 += __shfl_xor(a5, off, 64);
    a6 += __shfl_xor(a6, off, 64); a7 += __shfl_xor(a7, off, 64);
  }
  float dv = dinv2[wid];
  uint4 uo = hnq[(size_t)wid * 8 + lo8];
  a0 = fmaf(dv, bflo(uo.x), a0); a1 = fmaf(dv, bfhi(uo.x), a1);
  a2 = fmaf(dv, bflo(uo.y), a2); a3 = fmaf(dv, bfhi(uo.y), a3);
  a4 = fmaf(dv, bflo(uo.z), a4); a5 = fmaf(dv, bfhi(uo.z), a5);
  a6 = fmaf(dv, bflo(uo.w), a6); a7 = fmaf(dv, bfhi(uo.w), a7);
  if (lane < 8) {
    uint4 pv;
    pv.x = (u32)f2bf(dv * a0) | ((u32)f2bf(dv * a1) << 16);
    pv.y = (u32)f2bf(dv * a2) | ((u32)f2bf(dv * a3) << 16);
    pv.z = (u32)f2bf(dv * a4) | ((u32)f2bf(dv * a5) << 16);
    pv.w = (u32)f2bf(dv * a6) | ((u32)f2bf(dv * a7) << 16);
    agg2q[(size_t)wid * 8 + lo8] = pv;
  }
}

// ---------------- gemm2f: out = agg2b @ W2 + b2 (MFMA, fused bias, fp32 out) ----------------
#define G2S 72
__global__ __launch_bounds__(256) void k_gemm2f(const u16* __restrict__ aggb, const u16* __restrict__ W2t,
                                                const float* __restrict__ b2, float* __restrict__ out, int N) {
  __shared__ u16 hs[64 * G2S];
  __shared__ u16 ws[128 * G2S];
  int t = threadIdx.x;
  int wv = t >> 6, lane = t & 63;
  int qd = lane >> 4, md = lane & 15;
  int m0 = blockIdx.x * 64;
#pragma unroll
  for (int i = 0; i < 2; ++i) {                 // stage aggb: 64 rows x 64 u16 = 512 uint4
    int cc = t + 256 * i;
    int r = cc >> 3, kc = (cc & 7) * 8;
    int grow = m0 + r; if (grow >= N) grow = N - 1;
    *((uint4*)(hs + r * G2S + kc)) = *((const uint4*)(aggb + (size_t)grow * 64 + kc));
  }
#pragma unroll
  for (int i = 0; i < 4; ++i) {                 // stage W2t (128x64 u16)
    int cc = t + 256 * i;
    int n = cc >> 3, kc = (cc & 7) * 8;
    *((uint4*)(ws + n * G2S + kc)) = *((const uint4*)(W2t + n * 64 + kc));
  }
  __syncthreads();
  f4 acc[8] = {};
#pragma unroll
  for (int kk = 0; kk < 64; kk += 32) {
    bh8 af = *((const bh8*)(hs + (16 * wv + md) * G2S + kk + qd * 8));
#pragma unroll
    for (int nt = 0; nt < 8; ++nt) {
      bh8 bf = *((const bh8*)(ws + (nt * 16 + md) * G2S + kk + qd * 8));
      acc[nt] = mfma16(af, bf, acc[nt]);
    }
  }
#pragma unroll
  for (int nt = 0; nt < 8; ++nt) {
    float bv = b2[nt * 16 + md];
#pragma unroll
    for (int r = 0; r < 4; ++r) {
      int row = m0 + 16 * wv + qd * 4 + r;
      if (row < N) out[(size_t)row * 128 + nt * 16 + md] = acc[nt][r] + bv;
    }
  }
}

// ---------------- launch ----------------
extern "C" void kernel_launch(void* const* d_in, const int* in_sizes, int n_in,
                              void* d_out, int out_size, void* d_ws, size_t ws_size,
                              hipStream_t stream) {
  const float* x  = (const float*)d_in[0];
  const int*   ei = (const int*)d_in[1];
  const float* W1 = (const float*)d_in[2];
  const float* b1 = (const float*)d_in[3];
  const float* W2 = (const float*)d_in[4];
  const float* b2 = (const float*)d_in[5];
  const int N = in_sizes[0] / 256;
  const int E = in_sizes[1] / 2;
  const int nbS = (N + 511) >> 9;   // src buckets (98; <=128)
  const int nbD = (N + 127) >> 7;   // dst buckets (391; <=512)

  u32 sk1a, sk1b, sk2a, sk2b;
  tf2x32(0u, 42u, 0u, 0u, sk1a, sk1b);
  tf2x32(0u, 42u, 0u, 1u, sk2a, sk2b);

  char* p = (char*)d_ws;
  auto alloc = [&](size_t bytes) { char* r = p; p += (bytes + 255) & ~(size_t)255; return r; };
  // --- zero-init group (contiguous) ---
  int* dstCnt      = (int*)alloc((size_t)512 * CPAD * 4);   // padded: 1 counter / 64B line
  int* srcCnt      = (int*)alloc((size_t)128 * CPAD * 4);   // padded
  int* hcbA        = (int*)alloc((size_t)(1 + HMAX) * 4);
  int* hcbB        = (int*)alloc((size_t)(1 + HMAX) * 4);
  int* outdegB     = (int*)alloc((size_t)nbS * 512 * 4);
  int* dropCnt     = (int*)alloc(256);
  char* zero_end = p;
  // --- rest ---
  u32* dropList = (u32*)alloc((size_t)DROP_CAP * 4);
  u32* idAB     = (u32*)alloc((size_t)nbS * 512 * 4);
  u16* h1b      = (u16*)alloc((size_t)N * 64 * 2);
  u16* hnb      = (u16*)alloc((size_t)N * 64 * 2);
  u16* agg2b    = (u16*)alloc((size_t)N * 64 * 2);
  float* dinv1  = (float*)alloc((size_t)N * 4);
  float* dinv2  = (float*)alloc((size_t)N * 4);
  int* dptr     = (int*)alloc((size_t)(N + 1) * 4);
  int* bucketBase = (int*)alloc(513 * 4);
  u32* entries  = (u32*)alloc((size_t)E * 4);
  u32* srcRec   = (u32*)alloc((size_t)nbS * SB_CAP * 4);
  u64* dstRec   = (u64*)alloc((size_t)nbD * DB_CAP * 8);
  u64* bukA     = (u64*)alloc((size_t)HMAX * MAXD * 8);
  u64* bukB     = (u64*)alloc((size_t)HMAX * MAXD * 8);
  u16* W2t      = (u16*)alloc(64 * 128 * 2);

  int* hcA = hcbA; int* bcA = hcbA + 1;
  int* hcB = hcbB; int* bcB = hcbB + 1;

  hipMemsetAsync(dstCnt, 0x00, (size_t)(zero_end - (char*)dstCnt), stream);

  const int nBin = (E + SBCHUNK - 1) / SBCHUNK;
  const int nGemm = (N + 63) / 64;
  k_mega1<<<nBin + nGemm + 1, 256, 0, stream>>>(ei, E, x, N, W1, W2,
                                                srcCnt, srcRec, dstCnt, dstRec, h1b, W2t, nBin);
  k_shist<<<nbS * SPLIT, 256, 0, stream>>>(srcCnt, srcRec, outdegB);
  k_hdetect<<<(N + 255) / 256, 256, 0, stream>>>(outdegB, idAB, hcA, hcB, dstCnt, bucketBase,
                                                 dptr, nbD, N);
  k_hfill<<<nbS * SPLIT, 256, 0, stream>>>(srcCnt, srcRec, idAB, bcA, bukA, bcB, bukB,
                                           sk1a, sk1b, sk2a, sk2b);
  k_rank2<<<HMAX / 2, 256, 0, stream>>>(hcA, bcA, bukA, hcB, bcB, bukB, dropCnt, dropList);
  k_phase2<<<nbD, 256, 0, stream>>>(bucketBase, dstCnt, dstRec, dropCnt, dropList,
                                    entries, dptr, dinv1, dinv2, N);
  k_conv1n<<<(N * 64 + 255) / 256, 256, 0, stream>>>(dptr, entries, dinv1, (const uint4*)h1b, b1,
                                                     (uint4*)hnb, N);
  k_agg2<<<(N * 64 + 255) / 256, 256, 0, stream>>>(dptr, entries, dinv2, (const uint4*)hnb,
                                                   (uint4*)agg2b, N);
  k_gemm2f<<<(N + 63) / 64, 256, 0, stream>>>(agg2b, W2t, b2, (float*)d_out, N);
}